// Round 3
// baseline (790.879 us; speedup 1.0000x reference)
//
#include <hip/hip_runtime.h>
#include <stdint.h>

#define T_TOK 4096
#define H_DIM 1024
#define E_NUM 8
#define I_DIM 2048
#define CAP   9216   // max padded assignments: 8192 + 8*127 -> rounded up
#define MAXTILES 72  // CAP/128

typedef float f32x4 __attribute__((ext_vector_type(4)));
typedef __bf16 bf16x8 __attribute__((ext_vector_type(8)));

__device__ __forceinline__ unsigned short f2bf(float f) {
    union { float f; unsigned int u; } v; v.f = f;
    unsigned int u = v.u;
    return (unsigned short)((u + 0x7fffu + ((u >> 16) & 1u)) >> 16);  // RNE
}

// async global->LDS, 16B per lane. LDS dest = wave-uniform base + lane*16.
__device__ __forceinline__ void async16(const unsigned short* g, unsigned short* l) {
    __builtin_amdgcn_global_load_lds(
        (const __attribute__((address_space(1))) unsigned int*)g,
        (__attribute__((address_space(3))) unsigned int*)l,
        16, 0, 0);
}

// ---------- router: routes = x@Wr (fp32 exact), top2 + softmax, x -> bf16 ----------
__global__ __launch_bounds__(256)
void router_kernel(const float* __restrict__ x, const float* __restrict__ Wr,
                   unsigned short* __restrict__ xb, int* __restrict__ topidx,
                   float* __restrict__ topw, int* __restrict__ counts) {
    int t = blockIdx.x;
    int tid = threadIdx.x;
    const float* xrow = x + (size_t)t * H_DIM;
    float acc[E_NUM];
#pragma unroll
    for (int e = 0; e < E_NUM; e++) acc[e] = 0.f;
    for (int h = tid; h < H_DIM; h += 256) {
        float xv = xrow[h];
        xb[(size_t)t * H_DIM + h] = f2bf(xv);
        const float* wr = Wr + (size_t)h * E_NUM;
#pragma unroll
        for (int e = 0; e < E_NUM; e++) acc[e] += xv * wr[e];
    }
    __shared__ float red[256][E_NUM];
#pragma unroll
    for (int e = 0; e < E_NUM; e++) red[tid][e] = acc[e];
    __syncthreads();
    for (int s = 128; s > 0; s >>= 1) {
        if (tid < s) {
#pragma unroll
            for (int e = 0; e < E_NUM; e++) red[tid][e] += red[tid + s][e];
        }
        __syncthreads();
    }
    if (tid == 0) {
        float v0 = -1e30f; int i0 = 0;
        for (int e = 0; e < E_NUM; e++) { float v = red[0][e]; if (v > v0) { v0 = v; i0 = e; } }
        float v1 = -1e30f; int i1 = 1;
        for (int e = 0; e < E_NUM; e++) { if (e == i0) continue; float v = red[0][e]; if (v > v1) { v1 = v; i1 = e; } }
        float e1 = expf(v1 - v0);
        float s = 1.f + e1;
        topidx[t * 2 + 0] = i0; topidx[t * 2 + 1] = i1;
        topw[t * 2 + 0] = 1.f / s; topw[t * 2 + 1] = e1 / s;
        atomicAdd(&counts[i0], 1); atomicAdd(&counts[i1], 1);
    }
}

// ---------- offsets + XCD-interleaved flat tile map ----------
// Tiles emitted round-robin across experts: same-expert tiles land ~8 apart
// in blockIdx.x -> same XCD (blocks dispatched i%8) -> Wd/Wg/Wu slices hit L2.
__global__ void offsets_kernel(const int* __restrict__ counts, int* __restrict__ padded,
                               int* __restrict__ offs, int* __restrict__ tile_e,
                               int* __restrict__ tile_base, int* __restrict__ ntiles) {
    if (threadIdx.x == 0 && blockIdx.x == 0) {
        int off = 0;
        int nt_e[E_NUM], off_e[E_NUM];
        for (int e = 0; e < E_NUM; e++) {
            offs[e] = off;
            int p = (counts[e] + 127) & ~127;
            padded[e] = p;
            nt_e[e] = p >> 7;
            off_e[e] = off;
            off += p;
        }
        offs[E_NUM] = off;
        int t = 0;
        for (int r = 0; r < MAXTILES; r++)
            for (int e = 0; e < E_NUM; e++)
                if (r < nt_e[e]) { tile_e[t] = e; tile_base[t] = off_e[e] + (r << 7); t++; }
        ntiles[0] = t;
    }
}

// ---------- scatter assignments into per-expert lists + token->slot map ----------
__global__ __launch_bounds__(256)
void scatter_kernel(const int* __restrict__ topidx, const float* __restrict__ topw,
                    const int* __restrict__ offs, int* __restrict__ cursors,
                    int* __restrict__ list_tok, float* __restrict__ list_w,
                    int* __restrict__ slot_of) {
    int a = blockIdx.x * 256 + threadIdx.x;
    if (a >= T_TOK * 2) return;
    int e = topidx[a];
    int pos = atomicAdd(&cursors[e], 1);
    int slot = offs[e] + pos;
    list_tok[slot] = a >> 1;
    list_w[slot]   = topw[a];
    slot_of[a]     = slot;
}

// ---------- fill pad slots with token 0 / weight 0 ----------
__global__ void pad_kernel(const int* __restrict__ counts, const int* __restrict__ padded,
                           const int* __restrict__ offs, int* __restrict__ list_tok,
                           float* __restrict__ list_w) {
    int e = blockIdx.x;
    int pos = counts[e] + (int)threadIdx.x;
    if (pos < padded[e]) {
        list_tok[offs[e] + pos] = 0;
        list_w[offs[e] + pos]   = 0.f;
    }
}

// ---------- tiled transpose + fp32->bf16, float4 loads / 16B stores ----------
typedef unsigned short u16x8 __attribute__((ext_vector_type(8)));
__global__ __launch_bounds__(256)
void transpose_cvt(const float* __restrict__ in, unsigned short* __restrict__ out,
                   int R, int C) {
    __shared__ float tile[64][69];
    size_t mat = (size_t)R * C;
    const float* inp = in + (size_t)blockIdx.z * mat;
    unsigned short* outp = out + (size_t)blockIdx.z * mat;
    int c0 = blockIdx.x * 64, r0 = blockIdx.y * 64;
    int tid = threadIdx.x;
    int lc = (tid & 15) * 4, lr = tid >> 4;   // 16 lanes x float4 = 64 cols, 16 rows/pass
#pragma unroll
    for (int j = 0; j < 64; j += 16) {
        f32x4 v = *(const f32x4*)(inp + (size_t)(r0 + lr + j) * C + c0 + lc);
        tile[lr + j][lc + 0] = v[0]; tile[lr + j][lc + 1] = v[1];
        tile[lr + j][lc + 2] = v[2]; tile[lr + j][lc + 3] = v[3];
    }
    __syncthreads();
    int r8 = (tid & 7) * 8;                   // 8 lanes x 8 rows = 64 r per out-row
#pragma unroll
    for (int cc = 0; cc < 64; cc += 32) {
        int c = cc + (tid >> 3);
        u16x8 u;
#pragma unroll
        for (int j = 0; j < 8; j++) u[j] = f2bf(tile[r8 + j][c]);
        *(u16x8*)(outp + (size_t)(c0 + c) * R + r0 + r8) = u;
    }
}

// ---------- fused gate/up GEMM + SwiGLU, h pre-scaled by routing weight ----------
// LDS tiles unpadded (128B row stride) for global_load_lds;
// XOR chunk swizzle: row R, k-chunk c stored at c^(R&7) -> conflict-free reads.
__global__ __launch_bounds__(256, 3)
void gemm_gateup(const unsigned short* __restrict__ xb, const unsigned short* __restrict__ wgT,
                 const unsigned short* __restrict__ wuT, const int* __restrict__ list_tok,
                 const float* __restrict__ list_w,
                 const int* __restrict__ tile_e, const int* __restrict__ tile_base,
                 const int* __restrict__ ntiles, unsigned short* __restrict__ hbuf) {
    int tile = blockIdx.x;
    if (tile >= ntiles[0]) return;
    int e = tile_e[tile], base = tile_base[tile], nt = blockIdx.y;

    __shared__ unsigned short As[128 * 64];
    __shared__ unsigned short Bgs[128 * 64];
    __shared__ unsigned short Bus[128 * 64];
    __shared__ int toks[128];
    __shared__ float wsh[128];

    int tid = threadIdx.x;
    if (tid < 128) { toks[tid] = list_tok[base + tid]; wsh[tid] = list_w[base + tid]; }
    __syncthreads();

    const unsigned short* wg = wgT + ((size_t)e * I_DIM + (size_t)nt * 128) * H_DIM;
    const unsigned short* wu = wuT + ((size_t)e * I_DIM + (size_t)nt * 128) * H_DIM;

    int wv = tid >> 6, lane = tid & 63;
    int sr = lane >> 3, sc = lane & 7, gc = sc ^ sr;

    const unsigned short* ag[4]; const unsigned short* bgg[4]; const unsigned short* bug[4];
    int lb[4];
#pragma unroll
    for (int i = 0; i < 4; i++) {
        int row = wv * 32 + i * 8 + sr;
        ag[i]  = xb + (size_t)toks[row] * H_DIM + gc * 8;
        bgg[i] = wg + (size_t)row * H_DIM + gc * 8;
        bug[i] = wu + (size_t)row * H_DIM + gc * 8;
        lb[i]  = (wv * 32 + i * 8) * 64;
    }

    f32x4 accg[4][4], accu[4][4];
    f32x4 z = {0.f, 0.f, 0.f, 0.f};
#pragma unroll
    for (int i = 0; i < 4; i++)
#pragma unroll
        for (int j = 0; j < 4; j++) { accg[i][j] = z; accu[i][j] = z; }

    int wm = (wv >> 1) * 64, wn = (wv & 1) * 64;
    int l16 = lane & 15, quad = lane >> 4;

    for (int kb = 0; kb < H_DIM; kb += 64) {
#pragma unroll
        for (int i = 0; i < 4; i++) {
            async16(ag[i] + kb, &As[lb[i]]);
            async16(bgg[i] + kb, &Bgs[lb[i]]);
            async16(bug[i] + kb, &Bus[lb[i]]);
        }
        __syncthreads();
#pragma unroll
        for (int ks = 0; ks < 2; ks++) {
            bf16x8 af[4], bg4[4], bu4[4];
#pragma unroll
            for (int i = 0; i < 4; i++) {
                int row = wm + i * 16 + l16;
                int pos = ((ks * 4 + quad) ^ (row & 7)) * 8;
                af[i] = *(const bf16x8*)(&As[row * 64 + pos]);
            }
#pragma unroll
            for (int j = 0; j < 4; j++) {
                int row = wn + j * 16 + l16;
                int pos = ((ks * 4 + quad) ^ (row & 7)) * 8;
                bg4[j] = *(const bf16x8*)(&Bgs[row * 64 + pos]);
                bu4[j] = *(const bf16x8*)(&Bus[row * 64 + pos]);
            }
#pragma unroll
            for (int i = 0; i < 4; i++)
#pragma unroll
                for (int j = 0; j < 4; j++) {
                    accg[i][j] = __builtin_amdgcn_mfma_f32_16x16x32_bf16(af[i], bg4[j], accg[i][j], 0, 0, 0);
                    accu[i][j] = __builtin_amdgcn_mfma_f32_16x16x32_bf16(af[i], bu4[j], accu[i][j], 0, 0, 0);
                }
        }
        __syncthreads();
    }
#pragma unroll
    for (int i = 0; i < 4; i++) {
#pragma unroll
        for (int r = 0; r < 4; r++) {
            int row = wm + i * 16 + quad * 4 + r;     // C/D: col=lane&15, row=quad*4+reg
            float wgt = wsh[row];
            size_t hb = (size_t)(base + row) * I_DIM + (size_t)nt * 128 + wn;
#pragma unroll
            for (int j = 0; j < 4; j++) {
                float g = accg[i][j][r];
                float u = accu[i][j][r];
                float sig = 1.f / (1.f + __expf(-g));
                hbuf[hb + j * 16 + l16] = f2bf(g * sig * u * wgt);
            }
        }
    }
}

// ---------- down GEMM: dbuf[slot] = h[slot] @ Wd  (no atomics, w folded into h) ----------
__global__ __launch_bounds__(256, 4)
void gemm_down(const unsigned short* __restrict__ hbuf, const unsigned short* __restrict__ wdT,
               const int* __restrict__ tile_e, const int* __restrict__ tile_base,
               const int* __restrict__ ntiles, float* __restrict__ dbuf) {
    int tile = blockIdx.x;
    if (tile >= ntiles[0]) return;
    int e = tile_e[tile], base = tile_base[tile], nt = blockIdx.y;

    __shared__ unsigned short As[128 * 64];
    __shared__ unsigned short Bs[128 * 64];

    int tid = threadIdx.x;
    const unsigned short* wd = wdT + ((size_t)e * H_DIM + (size_t)nt * 128) * I_DIM;

    int wv = tid >> 6, lane = tid & 63;
    int sr = lane >> 3, sc = lane & 7, gc = sc ^ sr;

    const unsigned short* ag[4]; const unsigned short* bg[4];
    int lb[4];
#pragma unroll
    for (int i = 0; i < 4; i++) {
        int row = wv * 32 + i * 8 + sr;
        ag[i] = hbuf + (size_t)(base + row) * I_DIM + gc * 8;
        bg[i] = wd + (size_t)row * I_DIM + gc * 8;
        lb[i] = (wv * 32 + i * 8) * 64;
    }

    f32x4 acc[4][4];
    f32x4 z = {0.f, 0.f, 0.f, 0.f};
#pragma unroll
    for (int i = 0; i < 4; i++)
#pragma unroll
        for (int j = 0; j < 4; j++) acc[i][j] = z;

    int wm = (wv >> 1) * 64, wn = (wv & 1) * 64;
    int l16 = lane & 15, quad = lane >> 4;

    for (int kb = 0; kb < I_DIM; kb += 64) {
#pragma unroll
        for (int i = 0; i < 4; i++) {
            async16(ag[i] + kb, &As[lb[i]]);
            async16(bg[i] + kb, &Bs[lb[i]]);
        }
        __syncthreads();
#pragma unroll
        for (int ks = 0; ks < 2; ks++) {
            bf16x8 af[4], bf4[4];
#pragma unroll
            for (int i = 0; i < 4; i++) {
                int row = wm + i * 16 + l16;
                int pos = ((ks * 4 + quad) ^ (row & 7)) * 8;
                af[i] = *(const bf16x8*)(&As[row * 64 + pos]);
            }
#pragma unroll
            for (int j = 0; j < 4; j++) {
                int row = wn + j * 16 + l16;
                int pos = ((ks * 4 + quad) ^ (row & 7)) * 8;
                bf4[j] = *(const bf16x8*)(&Bs[row * 64 + pos]);
            }
#pragma unroll
            for (int i = 0; i < 4; i++)
#pragma unroll
                for (int j = 0; j < 4; j++)
                    acc[i][j] = __builtin_amdgcn_mfma_f32_16x16x32_bf16(af[i], bf4[j], acc[i][j], 0, 0, 0);
        }
        __syncthreads();
    }
#pragma unroll
    for (int i = 0; i < 4; i++) {
#pragma unroll
        for (int r = 0; r < 4; r++) {
            int row = wm + i * 16 + quad * 4 + r;
            float* orow = dbuf + (size_t)(base + row) * H_DIM + (size_t)nt * 128 + wn;
#pragma unroll
            for (int j = 0; j < 4; j++)
                orow[j * 16 + l16] = acc[i][j][r];
        }
    }
}

// ---------- combine: out[t] = dbuf[slot0] + dbuf[slot1] ----------
__global__ __launch_bounds__(256)
void combine_kernel(const float* __restrict__ dbuf, const int* __restrict__ slot_of,
                    float* __restrict__ out) {
    int t = blockIdx.x;
    int s0 = slot_of[2 * t], s1 = slot_of[2 * t + 1];
    const f32x4* r0 = (const f32x4*)(dbuf + (size_t)s0 * H_DIM);
    const f32x4* r1 = (const f32x4*)(dbuf + (size_t)s1 * H_DIM);
    f32x4* o = (f32x4*)(out + (size_t)t * H_DIM);
    int i = threadIdx.x;   // 256 threads x float4 = 1024 = H_DIM
    o[i] = r0[i] + r1[i];
}

extern "C" void kernel_launch(void* const* d_in, const int* in_sizes, int n_in,
                              void* d_out, int out_size, void* d_ws, size_t ws_size,
                              hipStream_t stream) {
    const float* x  = (const float*)d_in[0];
    const float* Wr = (const float*)d_in[1];
    const float* Wg = (const float*)d_in[2];
    const float* Wu = (const float*)d_in[3];
    const float* Wd = (const float*)d_in[4];
    float* out = (float*)d_out;
    char* ws = (char*)d_ws;

    size_t off = 0;
    unsigned short* xb   = (unsigned short*)(ws + off); off += (size_t)T_TOK * H_DIM * 2;
    unsigned short* wgT  = (unsigned short*)(ws + off); off += (size_t)E_NUM * H_DIM * I_DIM * 2;
    unsigned short* wuT  = (unsigned short*)(ws + off); off += (size_t)E_NUM * H_DIM * I_DIM * 2;
    unsigned short* wdT  = (unsigned short*)(ws + off); off += (size_t)E_NUM * H_DIM * I_DIM * 2;
    unsigned short* hbuf = (unsigned short*)(ws + off); off += (size_t)CAP * I_DIM * 2;
    float* dbuf    = (float*)(ws + off); off += (size_t)CAP * H_DIM * 4;
    int*   topidx  = (int*)(ws + off);   off += (size_t)T_TOK * 2 * 4;
    float* topw    = (float*)(ws + off); off += (size_t)T_TOK * 2 * 4;
    int*   slot_of = (int*)(ws + off);   off += (size_t)T_TOK * 2 * 4;
    int*   meta    = (int*)(ws + off);   off += 1024;
    int*   counts  = meta;          // 8
    int*   cursors = meta + 8;      // 8
    int*   padded  = meta + 16;     // 8
    int*   offs    = meta + 24;     // 9
    int*   ntiles  = meta + 33;     // 1
    int*   tile_e  = meta + 64;     // 72
    int*   tile_b  = meta + 136;    // 72
    int*   list_tok = (int*)(ws + off);  off += (size_t)CAP * 4;
    float* list_w   = (float*)(ws + off); off += (size_t)CAP * 4;

    hipMemsetAsync(counts, 0, 64, stream);  // counts + cursors

    router_kernel<<<T_TOK, 256, 0, stream>>>(x, Wr, xb, topidx, topw, counts);
    transpose_cvt<<<dim3(I_DIM / 64, H_DIM / 64, E_NUM), 256, 0, stream>>>(Wg, wgT, H_DIM, I_DIM);
    transpose_cvt<<<dim3(I_DIM / 64, H_DIM / 64, E_NUM), 256, 0, stream>>>(Wu, wuT, H_DIM, I_DIM);
    transpose_cvt<<<dim3(H_DIM / 64, I_DIM / 64, E_NUM), 256, 0, stream>>>(Wd, wdT, I_DIM, H_DIM);
    offsets_kernel<<<1, 1, 0, stream>>>(counts, padded, offs, tile_e, tile_b, ntiles);
    scatter_kernel<<<(T_TOK * 2) / 256, 256, 0, stream>>>(topidx, topw, offs, cursors, list_tok, list_w, slot_of);
    pad_kernel<<<E_NUM, 128, 0, stream>>>(counts, padded, offs, list_tok, list_w);
    gemm_gateup<<<dim3(MAXTILES, I_DIM / 128), 256, 0, stream>>>(xb, wgT, wuT, list_tok, list_w, tile_e, tile_b, ntiles, hbuf);
    gemm_down<<<dim3(MAXTILES, H_DIM / 128), 256, 0, stream>>>(hbuf, wdT, tile_e, tile_b, ntiles, dbuf);
    combine_kernel<<<T_TOK, 256, 0, stream>>>(dbuf, slot_of, out);
}

// Round 4
// 580.352 us; speedup vs baseline: 1.3628x; 1.3628x over previous
//
#include <hip/hip_runtime.h>
#include <stdint.h>

#define T_TOK 4096
#define H_DIM 1024
#define E_NUM 8
#define I_DIM 2048
#define CAP   9216   // max padded assignments: 8192 + 8*127 -> rounded up
#define MAXTILES 72  // CAP/128

typedef float f32x4 __attribute__((ext_vector_type(4)));
typedef __bf16 bf16x8 __attribute__((ext_vector_type(8)));

__device__ __forceinline__ unsigned short f2bf(float f) {
    union { float f; unsigned int u; } v; v.f = f;
    unsigned int u = v.u;
    return (unsigned short)((u + 0x7fffu + ((u >> 16) & 1u)) >> 16);  // RNE
}

// async global->LDS, 16B per lane. LDS dest = wave-uniform base + lane*16.
__device__ __forceinline__ void async16(const unsigned short* g, unsigned short* l) {
    __builtin_amdgcn_global_load_lds(
        (const __attribute__((address_space(1))) unsigned int*)g,
        (__attribute__((address_space(3))) unsigned int*)l,
        16, 0, 0);
}

// ---------- router: routes = x@Wr (fp32 exact), top2 + softmax, x -> bf16 ----------
__global__ __launch_bounds__(256)
void router_kernel(const float* __restrict__ x, const float* __restrict__ Wr,
                   unsigned short* __restrict__ xb, int* __restrict__ topidx,
                   float* __restrict__ topw, int* __restrict__ counts) {
    int t = blockIdx.x;
    int tid = threadIdx.x;
    const float* xrow = x + (size_t)t * H_DIM;
    float acc[E_NUM];
#pragma unroll
    for (int e = 0; e < E_NUM; e++) acc[e] = 0.f;
    for (int h = tid; h < H_DIM; h += 256) {
        float xv = xrow[h];
        xb[(size_t)t * H_DIM + h] = f2bf(xv);
        const float* wr = Wr + (size_t)h * E_NUM;
#pragma unroll
        for (int e = 0; e < E_NUM; e++) acc[e] += xv * wr[e];
    }
    __shared__ float red[256][E_NUM];
#pragma unroll
    for (int e = 0; e < E_NUM; e++) red[tid][e] = acc[e];
    __syncthreads();
    for (int s = 128; s > 0; s >>= 1) {
        if (tid < s) {
#pragma unroll
            for (int e = 0; e < E_NUM; e++) red[tid][e] += red[tid + s][e];
        }
        __syncthreads();
    }
    if (tid == 0) {
        float v0 = -1e30f; int i0 = 0;
        for (int e = 0; e < E_NUM; e++) { float v = red[0][e]; if (v > v0) { v0 = v; i0 = e; } }
        float v1 = -1e30f; int i1 = 1;
        for (int e = 0; e < E_NUM; e++) { if (e == i0) continue; float v = red[0][e]; if (v > v1) { v1 = v; i1 = e; } }
        float e1 = expf(v1 - v0);
        float s = 1.f + e1;
        topidx[t * 2 + 0] = i0; topidx[t * 2 + 1] = i1;
        topw[t * 2 + 0] = 1.f / s; topw[t * 2 + 1] = e1 / s;
        atomicAdd(&counts[i0], 1); atomicAdd(&counts[i1], 1);
    }
}

// ---------- offsets + XCD-interleaved flat tile map ----------
__global__ void offsets_kernel(const int* __restrict__ counts, int* __restrict__ padded,
                               int* __restrict__ offs, int* __restrict__ tile_e,
                               int* __restrict__ tile_base, int* __restrict__ ntiles) {
    if (threadIdx.x == 0 && blockIdx.x == 0) {
        int off = 0;
        int nt_e[E_NUM], off_e[E_NUM];
        for (int e = 0; e < E_NUM; e++) {
            offs[e] = off;
            int p = (counts[e] + 127) & ~127;
            padded[e] = p;
            nt_e[e] = p >> 7;
            off_e[e] = off;
            off += p;
        }
        offs[E_NUM] = off;
        int t = 0;
        for (int r = 0; r < MAXTILES; r++)
            for (int e = 0; e < E_NUM; e++)
                if (r < nt_e[e]) { tile_e[t] = e; tile_base[t] = off_e[e] + (r << 7); t++; }
        ntiles[0] = t;
    }
}

// ---------- scatter assignments into per-expert lists + token->slot map ----------
__global__ __launch_bounds__(256)
void scatter_kernel(const int* __restrict__ topidx, const float* __restrict__ topw,
                    const int* __restrict__ offs, int* __restrict__ cursors,
                    int* __restrict__ list_tok, float* __restrict__ list_w,
                    int* __restrict__ slot_of) {
    int a = blockIdx.x * 256 + threadIdx.x;
    if (a >= T_TOK * 2) return;
    int e = topidx[a];
    int pos = atomicAdd(&cursors[e], 1);
    int slot = offs[e] + pos;
    list_tok[slot] = a >> 1;
    list_w[slot]   = topw[a];
    slot_of[a]     = slot;
}

// ---------- fill pad slots with token 0 / weight 0 ----------
__global__ void pad_kernel(const int* __restrict__ counts, const int* __restrict__ padded,
                           const int* __restrict__ offs, int* __restrict__ list_tok,
                           float* __restrict__ list_w) {
    int e = blockIdx.x;
    int pos = counts[e] + (int)threadIdx.x;
    if (pos < padded[e]) {
        list_tok[offs[e] + pos] = 0;
        list_w[offs[e] + pos]   = 0.f;
    }
}

// ---------- tiled transpose + fp32->bf16, float4 loads / 16B stores ----------
typedef unsigned short u16x8 __attribute__((ext_vector_type(8)));
__global__ __launch_bounds__(256)
void transpose_cvt(const float* __restrict__ in, unsigned short* __restrict__ out,
                   int R, int C) {
    __shared__ float tile[64][69];
    size_t mat = (size_t)R * C;
    const float* inp = in + (size_t)blockIdx.z * mat;
    unsigned short* outp = out + (size_t)blockIdx.z * mat;
    int c0 = blockIdx.x * 64, r0 = blockIdx.y * 64;
    int tid = threadIdx.x;
    int lc = (tid & 15) * 4, lr = tid >> 4;   // 16 lanes x float4 = 64 cols, 16 rows/pass
#pragma unroll
    for (int j = 0; j < 64; j += 16) {
        f32x4 v = *(const f32x4*)(inp + (size_t)(r0 + lr + j) * C + c0 + lc);
        tile[lr + j][lc + 0] = v[0]; tile[lr + j][lc + 1] = v[1];
        tile[lr + j][lc + 2] = v[2]; tile[lr + j][lc + 3] = v[3];
    }
    __syncthreads();
    int r8 = (tid & 7) * 8;                   // 8 lanes x 8 rows = 64 r per out-row
#pragma unroll
    for (int cc = 0; cc < 64; cc += 32) {
        int c = cc + (tid >> 3);
        u16x8 u;
#pragma unroll
        for (int j = 0; j < 8; j++) u[j] = f2bf(tile[r8 + j][c]);
        *(u16x8*)(outp + (size_t)(c0 + c) * R + r0 + r8) = u;
    }
}

// ---------- fused gate/up GEMM + SwiGLU, h pre-scaled by routing weight ----------
// LDS tiles unpadded (128B row stride) for global_load_lds;
// XOR chunk swizzle: row R, k-chunk c stored at c^(R&7) -> conflict-free reads.
// launch_bounds(256,2): 128 acc regs + ~48 frag/addr NEED the 256-reg budget;
// (256,3) capped at ~170 and spilled accumulators (r3: WRITE 663MB, 324us).
__global__ __launch_bounds__(256, 2)
void gemm_gateup(const unsigned short* __restrict__ xb, const unsigned short* __restrict__ wgT,
                 const unsigned short* __restrict__ wuT, const int* __restrict__ list_tok,
                 const float* __restrict__ list_w,
                 const int* __restrict__ tile_e, const int* __restrict__ tile_base,
                 const int* __restrict__ ntiles, unsigned short* __restrict__ hbuf) {
    int tile = blockIdx.x;
    if (tile >= ntiles[0]) return;
    int e = tile_e[tile], base = tile_base[tile], nt = blockIdx.y;

    __shared__ unsigned short As[128 * 64];
    __shared__ unsigned short Bgs[128 * 64];
    __shared__ unsigned short Bus[128 * 64];
    __shared__ int toks[128];
    __shared__ float wsh[128];

    int tid = threadIdx.x;
    if (tid < 128) { toks[tid] = list_tok[base + tid]; wsh[tid] = list_w[base + tid]; }
    __syncthreads();

    const unsigned short* wg = wgT + ((size_t)e * I_DIM + (size_t)nt * 128) * H_DIM;
    const unsigned short* wu = wuT + ((size_t)e * I_DIM + (size_t)nt * 128) * H_DIM;

    int wv = tid >> 6, lane = tid & 63;
    int sr = lane >> 3, sc = lane & 7, gc = sc ^ sr;

    const unsigned short* ag[4]; const unsigned short* bgg[4]; const unsigned short* bug[4];
    int lb[4];
#pragma unroll
    for (int i = 0; i < 4; i++) {
        int row = wv * 32 + i * 8 + sr;
        ag[i]  = xb + (size_t)toks[row] * H_DIM + gc * 8;
        bgg[i] = wg + (size_t)row * H_DIM + gc * 8;
        bug[i] = wu + (size_t)row * H_DIM + gc * 8;
        lb[i]  = (wv * 32 + i * 8) * 64;
    }

    f32x4 accg[4][4], accu[4][4];
    f32x4 z = {0.f, 0.f, 0.f, 0.f};
#pragma unroll
    for (int i = 0; i < 4; i++)
#pragma unroll
        for (int j = 0; j < 4; j++) { accg[i][j] = z; accu[i][j] = z; }

    int wm = (wv >> 1) * 64, wn = (wv & 1) * 64;
    int l16 = lane & 15, quad = lane >> 4;

    for (int kb = 0; kb < H_DIM; kb += 64) {
#pragma unroll
        for (int i = 0; i < 4; i++) {
            async16(ag[i] + kb, &As[lb[i]]);
            async16(bgg[i] + kb, &Bgs[lb[i]]);
            async16(bug[i] + kb, &Bus[lb[i]]);
        }
        __syncthreads();
#pragma unroll
        for (int ks = 0; ks < 2; ks++) {
            bf16x8 af[4], bg4[4], bu4[4];
#pragma unroll
            for (int i = 0; i < 4; i++) {
                int row = wm + i * 16 + l16;
                int pos = ((ks * 4 + quad) ^ (row & 7)) * 8;
                af[i] = *(const bf16x8*)(&As[row * 64 + pos]);
            }
#pragma unroll
            for (int j = 0; j < 4; j++) {
                int row = wn + j * 16 + l16;
                int pos = ((ks * 4 + quad) ^ (row & 7)) * 8;
                bg4[j] = *(const bf16x8*)(&Bgs[row * 64 + pos]);
                bu4[j] = *(const bf16x8*)(&Bus[row * 64 + pos]);
            }
#pragma unroll
            for (int i = 0; i < 4; i++)
#pragma unroll
                for (int j = 0; j < 4; j++) {
                    accg[i][j] = __builtin_amdgcn_mfma_f32_16x16x32_bf16(af[i], bg4[j], accg[i][j], 0, 0, 0);
                    accu[i][j] = __builtin_amdgcn_mfma_f32_16x16x32_bf16(af[i], bu4[j], accu[i][j], 0, 0, 0);
                }
        }
        __syncthreads();
    }
#pragma unroll
    for (int i = 0; i < 4; i++) {
#pragma unroll
        for (int r = 0; r < 4; r++) {
            int row = wm + i * 16 + quad * 4 + r;     // C/D: col=lane&15, row=quad*4+reg
            float wgt = wsh[row];
            size_t hb = (size_t)(base + row) * I_DIM + (size_t)nt * 128 + wn;
#pragma unroll
            for (int j = 0; j < 4; j++) {
                float g = accg[i][j][r];
                float u = accu[i][j][r];
                float sig = 1.f / (1.f + __expf(-g));
                hbuf[hb + j * 16 + l16] = f2bf(g * sig * u * wgt);
            }
        }
    }
}

// ---------- down GEMM: dbuf[slot] = h[slot] @ Wd  (no atomics, w folded into h) ----------
__global__ __launch_bounds__(256, 4)
void gemm_down(const unsigned short* __restrict__ hbuf, const unsigned short* __restrict__ wdT,
               const int* __restrict__ tile_e, const int* __restrict__ tile_base,
               const int* __restrict__ ntiles, float* __restrict__ dbuf) {
    int tile = blockIdx.x;
    if (tile >= ntiles[0]) return;
    int e = tile_e[tile], base = tile_base[tile], nt = blockIdx.y;

    __shared__ unsigned short As[128 * 64];
    __shared__ unsigned short Bs[128 * 64];

    int tid = threadIdx.x;
    const unsigned short* wd = wdT + ((size_t)e * H_DIM + (size_t)nt * 128) * I_DIM;

    int wv = tid >> 6, lane = tid & 63;
    int sr = lane >> 3, sc = lane & 7, gc = sc ^ sr;

    const unsigned short* ag[4]; const unsigned short* bg[4];
    int lb[4];
#pragma unroll
    for (int i = 0; i < 4; i++) {
        int row = wv * 32 + i * 8 + sr;
        ag[i] = hbuf + (size_t)(base + row) * I_DIM + gc * 8;
        bg[i] = wd + (size_t)row * I_DIM + gc * 8;
        lb[i] = (wv * 32 + i * 8) * 64;
    }

    f32x4 acc[4][4];
    f32x4 z = {0.f, 0.f, 0.f, 0.f};
#pragma unroll
    for (int i = 0; i < 4; i++)
#pragma unroll
        for (int j = 0; j < 4; j++) acc[i][j] = z;

    int wm = (wv >> 1) * 64, wn = (wv & 1) * 64;
    int l16 = lane & 15, quad = lane >> 4;

    for (int kb = 0; kb < I_DIM; kb += 64) {
#pragma unroll
        for (int i = 0; i < 4; i++) {
            async16(ag[i] + kb, &As[lb[i]]);
            async16(bg[i] + kb, &Bs[lb[i]]);
        }
        __syncthreads();
#pragma unroll
        for (int ks = 0; ks < 2; ks++) {
            bf16x8 af[4], bf4[4];
#pragma unroll
            for (int i = 0; i < 4; i++) {
                int row = wm + i * 16 + l16;
                int pos = ((ks * 4 + quad) ^ (row & 7)) * 8;
                af[i] = *(const bf16x8*)(&As[row * 64 + pos]);
            }
#pragma unroll
            for (int j = 0; j < 4; j++) {
                int row = wn + j * 16 + l16;
                int pos = ((ks * 4 + quad) ^ (row & 7)) * 8;
                bf4[j] = *(const bf16x8*)(&Bs[row * 64 + pos]);
            }
#pragma unroll
            for (int i = 0; i < 4; i++)
#pragma unroll
                for (int j = 0; j < 4; j++)
                    acc[i][j] = __builtin_amdgcn_mfma_f32_16x16x32_bf16(af[i], bf4[j], acc[i][j], 0, 0, 0);
        }
        __syncthreads();
    }
#pragma unroll
    for (int i = 0; i < 4; i++) {
#pragma unroll
        for (int r = 0; r < 4; r++) {
            int row = wm + i * 16 + quad * 4 + r;
            float* orow = dbuf + (size_t)(base + row) * H_DIM + (size_t)nt * 128 + wn;
#pragma unroll
            for (int j = 0; j < 4; j++)
                orow[j * 16 + l16] = acc[i][j][r];
        }
    }
}

// ---------- combine: out[t] = dbuf[slot0] + dbuf[slot1] ----------
__global__ __launch_bounds__(256)
void combine_kernel(const float* __restrict__ dbuf, const int* __restrict__ slot_of,
                    float* __restrict__ out) {
    int t = blockIdx.x;
    int s0 = slot_of[2 * t], s1 = slot_of[2 * t + 1];
    const f32x4* r0 = (const f32x4*)(dbuf + (size_t)s0 * H_DIM);
    const f32x4* r1 = (const f32x4*)(dbuf + (size_t)s1 * H_DIM);
    f32x4* o = (f32x4*)(out + (size_t)t * H_DIM);
    int i = threadIdx.x;   // 256 threads x float4 = 1024 = H_DIM
    o[i] = r0[i] + r1[i];
}

extern "C" void kernel_launch(void* const* d_in, const int* in_sizes, int n_in,
                              void* d_out, int out_size, void* d_ws, size_t ws_size,
                              hipStream_t stream) {
    const float* x  = (const float*)d_in[0];
    const float* Wr = (const float*)d_in[1];
    const float* Wg = (const float*)d_in[2];
    const float* Wu = (const float*)d_in[3];
    const float* Wd = (const float*)d_in[4];
    float* out = (float*)d_out;
    char* ws = (char*)d_ws;

    size_t off = 0;
    unsigned short* xb   = (unsigned short*)(ws + off); off += (size_t)T_TOK * H_DIM * 2;
    unsigned short* wgT  = (unsigned short*)(ws + off); off += (size_t)E_NUM * H_DIM * I_DIM * 2;
    unsigned short* wuT  = (unsigned short*)(ws + off); off += (size_t)E_NUM * H_DIM * I_DIM * 2;
    unsigned short* wdT  = (unsigned short*)(ws + off); off += (size_t)E_NUM * H_DIM * I_DIM * 2;
    unsigned short* hbuf = (unsigned short*)(ws + off); off += (size_t)CAP * I_DIM * 2;
    float* dbuf    = (float*)(ws + off); off += (size_t)CAP * H_DIM * 4;
    int*   topidx  = (int*)(ws + off);   off += (size_t)T_TOK * 2 * 4;
    float* topw    = (float*)(ws + off); off += (size_t)T_TOK * 2 * 4;
    int*   slot_of = (int*)(ws + off);   off += (size_t)T_TOK * 2 * 4;
    int*   meta    = (int*)(ws + off);   off += 1024;
    int*   counts  = meta;          // 8
    int*   cursors = meta + 8;      // 8
    int*   padded  = meta + 16;     // 8
    int*   offs    = meta + 24;     // 9
    int*   ntiles  = meta + 33;     // 1
    int*   tile_e  = meta + 64;     // 72
    int*   tile_b  = meta + 136;    // 72
    int*   list_tok = (int*)(ws + off);  off += (size_t)CAP * 4;
    float* list_w   = (float*)(ws + off); off += (size_t)CAP * 4;

    hipMemsetAsync(counts, 0, 64, stream);  // counts + cursors

    router_kernel<<<T_TOK, 256, 0, stream>>>(x, Wr, xb, topidx, topw, counts);
    transpose_cvt<<<dim3(I_DIM / 64, H_DIM / 64, E_NUM), 256, 0, stream>>>(Wg, wgT, H_DIM, I_DIM);
    transpose_cvt<<<dim3(I_DIM / 64, H_DIM / 64, E_NUM), 256, 0, stream>>>(Wu, wuT, H_DIM, I_DIM);
    transpose_cvt<<<dim3(H_DIM / 64, I_DIM / 64, E_NUM), 256, 0, stream>>>(Wd, wdT, I_DIM, H_DIM);
    offsets_kernel<<<1, 1, 0, stream>>>(counts, padded, offs, tile_e, tile_b, ntiles);
    scatter_kernel<<<(T_TOK * 2) / 256, 256, 0, stream>>>(topidx, topw, offs, cursors, list_tok, list_w, slot_of);
    pad_kernel<<<E_NUM, 128, 0, stream>>>(counts, padded, offs, list_tok, list_w);
    gemm_gateup<<<dim3(MAXTILES, I_DIM / 128), 256, 0, stream>>>(xb, wgT, wuT, list_tok, list_w, tile_e, tile_b, ntiles, hbuf);
    gemm_down<<<dim3(MAXTILES, H_DIM / 128), 256, 0, stream>>>(hbuf, wdT, tile_e, tile_b, ntiles, dbuf);
    combine_kernel<<<T_TOK, 256, 0, stream>>>(dbuf, slot_of, out);
}

// Round 5
// 579.537 us; speedup vs baseline: 1.3647x; 1.0014x over previous
//
#include <hip/hip_runtime.h>
#include <stdint.h>

#define T_TOK 4096
#define H_DIM 1024
#define E_NUM 8
#define I_DIM 2048
#define CAP   9216   // max padded assignments: 8192 + 8*127 -> rounded up
#define MAXTILES 72  // CAP/128

typedef float f32x4 __attribute__((ext_vector_type(4)));
typedef __bf16 bf16x8 __attribute__((ext_vector_type(8)));
typedef unsigned short u16x8 __attribute__((ext_vector_type(8)));

__device__ __forceinline__ unsigned short f2bf(float f) {
    union { float f; unsigned int u; } v; v.f = f;
    unsigned int u = v.u;
    return (unsigned short)((u + 0x7fffu + ((u >> 16) & 1u)) >> 16);  // RNE
}

// async global->LDS, 16B per lane. LDS dest = wave-uniform base + lane*16.
__device__ __forceinline__ void async16(const unsigned short* g, unsigned short* l) {
    __builtin_amdgcn_global_load_lds(
        (const __attribute__((address_space(1))) unsigned int*)g,
        (__attribute__((address_space(3))) unsigned int*)l,
        16, 0, 0);
}

// ---------- router: wave per token, butterfly reduce; also x -> bf16 ----------
__global__ __launch_bounds__(256)
void router_kernel(const float* __restrict__ x, const float* __restrict__ Wr,
                   unsigned short* __restrict__ xb, int* __restrict__ topidx,
                   float* __restrict__ topw, int* __restrict__ counts) {
    int wv = threadIdx.x >> 6, lane = threadIdx.x & 63;
    int t = blockIdx.x * 4 + wv;
    const float* xrow = x + (size_t)t * H_DIM + lane * 16;
    const float* wrow = Wr + (size_t)lane * 16 * E_NUM;
    float acc[E_NUM];
#pragma unroll
    for (int e = 0; e < E_NUM; e++) acc[e] = 0.f;
    unsigned short xo[16];
#pragma unroll
    for (int c = 0; c < 4; c++) {
        f32x4 xv = *(const f32x4*)(xrow + c * 4);
#pragma unroll
        for (int k = 0; k < 4; k++) {
            float v = xv[k];
            xo[c * 4 + k] = f2bf(v);
            const float* wr = wrow + (c * 4 + k) * E_NUM;
#pragma unroll
            for (int e = 0; e < E_NUM; e++) acc[e] += v * wr[e];
        }
    }
    unsigned short* xbp = xb + (size_t)t * H_DIM + lane * 16;
    *(u16x8*)xbp = *(u16x8*)xo;
    *(u16x8*)(xbp + 8) = *(u16x8*)(xo + 8);
#pragma unroll
    for (int m = 1; m < 64; m <<= 1) {
#pragma unroll
        for (int e = 0; e < E_NUM; e++) acc[e] += __shfl_xor(acc[e], m);
    }
    if (lane == 0) {
        float v0 = -1e30f; int i0 = 0;
#pragma unroll
        for (int e = 0; e < E_NUM; e++) { if (acc[e] > v0) { v0 = acc[e]; i0 = e; } }
        float v1 = -1e30f; int i1 = 0;
#pragma unroll
        for (int e = 0; e < E_NUM; e++) { if (e != i0 && acc[e] > v1) { v1 = acc[e]; i1 = e; } }
        float e1 = __expf(v1 - v0);
        float s = 1.f + e1;
        topidx[t * 2 + 0] = i0; topidx[t * 2 + 1] = i1;
        topw[t * 2 + 0] = 1.f / s; topw[t * 2 + 1] = e1 / s;
        atomicAdd(&counts[i0], 1); atomicAdd(&counts[i1], 1);
    }
}

// ---------- offsets + XCD-interleaved tile map + pad fill, one 256-thread block ----------
__global__ __launch_bounds__(256)
void offsets_pad_kernel(const int* __restrict__ counts, int* __restrict__ padded,
                        int* __restrict__ offs, int* __restrict__ tile_e,
                        int* __restrict__ tile_base, int* __restrict__ ntiles,
                        int* __restrict__ list_tok, float* __restrict__ list_w) {
    __shared__ int sc[E_NUM], sp[E_NUM], so[E_NUM + 1], snt;
    __shared__ int ste[MAXTILES], stb[MAXTILES];
    int tid = threadIdx.x;
    if (tid < MAXTILES) { ste[tid] = 0; stb[tid] = 0; }
    if (tid == 0) {
        int off = 0, nt_e[E_NUM];
        for (int e = 0; e < E_NUM; e++) {
            sc[e] = counts[e];
            so[e] = off;
            int p = (sc[e] + 127) & ~127;
            sp[e] = p; nt_e[e] = p >> 7; off += p;
        }
        so[E_NUM] = off;
        int t2 = 0;
        // round-robin across experts: same-expert tiles ~8 apart -> same XCD
        for (int r = 0; r < MAXTILES; r++)
            for (int e = 0; e < E_NUM; e++)
                if (r < nt_e[e]) { ste[t2] = e; stb[t2] = so[e] + (r << 7); t2++; }
        snt = t2;
    }
    __syncthreads();
    if (tid < E_NUM) { padded[tid] = sp[tid]; offs[tid] = so[tid]; }
    if (tid == E_NUM) { offs[E_NUM] = so[E_NUM]; ntiles[0] = snt; }
    if (tid < MAXTILES) { tile_e[tid] = ste[tid]; tile_base[tid] = stb[tid]; }
#pragma unroll
    for (int e = 0; e < E_NUM; e++)
        for (int pos = sc[e] + tid; pos < sp[e]; pos += 256) {
            list_tok[so[e] + pos] = 0;
            list_w[so[e] + pos] = 0.f;
        }
}

// ---------- scatter assignments into per-expert lists + token->slot map ----------
__global__ __launch_bounds__(256)
void scatter_kernel(const int* __restrict__ topidx, const float* __restrict__ topw,
                    const int* __restrict__ offs, int* __restrict__ cursors,
                    int* __restrict__ list_tok, float* __restrict__ list_w,
                    int* __restrict__ slot_of) {
    int a = blockIdx.x * 256 + threadIdx.x;
    if (a >= T_TOK * 2) return;
    int e = topidx[a];
    int pos = atomicAdd(&cursors[e], 1);
    int slot = offs[e] + pos;
    list_tok[slot] = a >> 1;
    list_w[slot]   = topw[a];
    slot_of[a]     = slot;
}

// ---------- fused transpose + fp32->bf16 for all three weight tensors ----------
// z in [0,8): Wg expert z; [8,16): Wu; [16,24): Wd (swapped tile roles).
__global__ __launch_bounds__(256)
void transpose_all(const float* __restrict__ Wg, const float* __restrict__ Wu,
                   const float* __restrict__ Wd, unsigned short* __restrict__ wgT,
                   unsigned short* __restrict__ wuT, unsigned short* __restrict__ wdT) {
    __shared__ float tile[64][69];
    int z = blockIdx.z, bx = blockIdx.x, by = blockIdx.y;
    const float* in; unsigned short* out;
    int R, C, c0, r0;
    size_t mat = (size_t)H_DIM * I_DIM;
    if (z < 16) {               // Wg/Wu: R=H=1024, C=I=2048
        int e = z & 7;
        in  = (z < 8 ? Wg : Wu) + (size_t)e * mat;
        out = (z < 8 ? wgT : wuT) + (size_t)e * mat;
        R = H_DIM; C = I_DIM;
        c0 = bx * 64; r0 = by * 64;      // bx 0..31, by 0..15
    } else {                    // Wd: R=I=2048, C=H=1024
        int e = z - 16;
        in  = Wd + (size_t)e * mat;
        out = wdT + (size_t)e * mat;
        R = I_DIM; C = H_DIM;
        c0 = by * 64; r0 = bx * 64;      // by 0..15, bx 0..31
    }
    int tid = threadIdx.x;
    int lc = (tid & 15) * 4, lr = tid >> 4;   // 16 lanes x float4 = 64 cols, 16 rows/pass
#pragma unroll
    for (int j = 0; j < 64; j += 16) {
        f32x4 v = *(const f32x4*)(in + (size_t)(r0 + lr + j) * C + c0 + lc);
        tile[lr + j][lc + 0] = v[0]; tile[lr + j][lc + 1] = v[1];
        tile[lr + j][lc + 2] = v[2]; tile[lr + j][lc + 3] = v[3];
    }
    __syncthreads();
    int r8 = (tid & 7) * 8;                   // 8 lanes x 8 rows
#pragma unroll
    for (int cc = 0; cc < 64; cc += 32) {
        int c = cc + (tid >> 3);
        u16x8 u;
#pragma unroll
        for (int j = 0; j < 8; j++) u[j] = f2bf(tile[r8 + j][c]);
        *(u16x8*)(out + (size_t)(c0 + c) * R + r0 + r8) = u;
    }
}

// ---------- fused gate/up GEMM + SwiGLU, h pre-scaled by routing weight ----------
// LDS tiles unpadded (128B row stride) for global_load_lds;
// XOR chunk swizzle: row R, k-chunk c stored at c^(R&7) -> conflict-free reads.
// launch_bounds(256,2): 128 acc regs + ~48 frag/addr NEED the 256-reg budget;
// (256,3) capped at ~170 and spilled accumulators (r3: WRITE 663MB, 324us).
__global__ __launch_bounds__(256, 2)
void gemm_gateup(const unsigned short* __restrict__ xb, const unsigned short* __restrict__ wgT,
                 const unsigned short* __restrict__ wuT, const int* __restrict__ list_tok,
                 const float* __restrict__ list_w,
                 const int* __restrict__ tile_e, const int* __restrict__ tile_base,
                 const int* __restrict__ ntiles, unsigned short* __restrict__ hbuf) {
    int tile = blockIdx.x;
    if (tile >= ntiles[0]) return;
    int e = tile_e[tile], base = tile_base[tile], nt = blockIdx.y;

    __shared__ unsigned short As[128 * 64];
    __shared__ unsigned short Bgs[128 * 64];
    __shared__ unsigned short Bus[128 * 64];
    __shared__ int toks[128];
    __shared__ float wsh[128];

    int tid = threadIdx.x;
    if (tid < 128) { toks[tid] = list_tok[base + tid]; wsh[tid] = list_w[base + tid]; }
    __syncthreads();

    const unsigned short* wg = wgT + ((size_t)e * I_DIM + (size_t)nt * 128) * H_DIM;
    const unsigned short* wu = wuT + ((size_t)e * I_DIM + (size_t)nt * 128) * H_DIM;

    int wv = tid >> 6, lane = tid & 63;
    int sr = lane >> 3, sc = lane & 7, gc = sc ^ sr;

    const unsigned short* ag[4]; const unsigned short* bgg[4]; const unsigned short* bug[4];
    int lb[4];
#pragma unroll
    for (int i = 0; i < 4; i++) {
        int row = wv * 32 + i * 8 + sr;
        ag[i]  = xb + (size_t)toks[row] * H_DIM + gc * 8;
        bgg[i] = wg + (size_t)row * H_DIM + gc * 8;
        bug[i] = wu + (size_t)row * H_DIM + gc * 8;
        lb[i]  = (wv * 32 + i * 8) * 64;
    }

    f32x4 accg[4][4], accu[4][4];
    f32x4 z = {0.f, 0.f, 0.f, 0.f};
#pragma unroll
    for (int i = 0; i < 4; i++)
#pragma unroll
        for (int j = 0; j < 4; j++) { accg[i][j] = z; accu[i][j] = z; }

    int wm = (wv >> 1) * 64, wn = (wv & 1) * 64;
    int l16 = lane & 15, quad = lane >> 4;

    for (int kb = 0; kb < H_DIM; kb += 64) {
#pragma unroll
        for (int i = 0; i < 4; i++) {
            async16(ag[i] + kb, &As[lb[i]]);
            async16(bgg[i] + kb, &Bgs[lb[i]]);
            async16(bug[i] + kb, &Bus[lb[i]]);
        }
        __syncthreads();
#pragma unroll
        for (int ks = 0; ks < 2; ks++) {
            bf16x8 af[4], bg4[4], bu4[4];
#pragma unroll
            for (int i = 0; i < 4; i++) {
                int row = wm + i * 16 + l16;
                int pos = ((ks * 4 + quad) ^ (row & 7)) * 8;
                af[i] = *(const bf16x8*)(&As[row * 64 + pos]);
            }
#pragma unroll
            for (int j = 0; j < 4; j++) {
                int row = wn + j * 16 + l16;
                int pos = ((ks * 4 + quad) ^ (row & 7)) * 8;
                bg4[j] = *(const bf16x8*)(&Bgs[row * 64 + pos]);
                bu4[j] = *(const bf16x8*)(&Bus[row * 64 + pos]);
            }
#pragma unroll
            for (int i = 0; i < 4; i++)
#pragma unroll
                for (int j = 0; j < 4; j++) {
                    accg[i][j] = __builtin_amdgcn_mfma_f32_16x16x32_bf16(af[i], bg4[j], accg[i][j], 0, 0, 0);
                    accu[i][j] = __builtin_amdgcn_mfma_f32_16x16x32_bf16(af[i], bu4[j], accu[i][j], 0, 0, 0);
                }
        }
        __syncthreads();
    }
#pragma unroll
    for (int i = 0; i < 4; i++) {
#pragma unroll
        for (int r = 0; r < 4; r++) {
            int row = wm + i * 16 + quad * 4 + r;     // C/D: col=lane&15, row=quad*4+reg
            float wgt = wsh[row];
            size_t hb = (size_t)(base + row) * I_DIM + (size_t)nt * 128 + wn;
#pragma unroll
            for (int j = 0; j < 4; j++) {
                float g = accg[i][j][r];
                float u = accu[i][j][r];
                float sig = 1.f / (1.f + __expf(-g));
                hbuf[hb + j * 16 + l16] = f2bf(g * sig * u * wgt);
            }
        }
    }
}

// ---------- down GEMM: dbuf[slot] = h[slot] @ Wd  (no atomics, w folded into h) ----------
__global__ __launch_bounds__(256, 4)
void gemm_down(const unsigned short* __restrict__ hbuf, const unsigned short* __restrict__ wdT,
               const int* __restrict__ tile_e, const int* __restrict__ tile_base,
               const int* __restrict__ ntiles, float* __restrict__ dbuf) {
    int tile = blockIdx.x;
    if (tile >= ntiles[0]) return;
    int e = tile_e[tile], base = tile_base[tile], nt = blockIdx.y;

    __shared__ unsigned short As[128 * 64];
    __shared__ unsigned short Bs[128 * 64];

    int tid = threadIdx.x;
    const unsigned short* wd = wdT + ((size_t)e * H_DIM + (size_t)nt * 128) * I_DIM;

    int wv = tid >> 6, lane = tid & 63;
    int sr = lane >> 3, sc = lane & 7, gc = sc ^ sr;

    const unsigned short* ag[4]; const unsigned short* bg[4];
    int lb[4];
#pragma unroll
    for (int i = 0; i < 4; i++) {
        int row = wv * 32 + i * 8 + sr;
        ag[i] = hbuf + (size_t)(base + row) * I_DIM + gc * 8;
        bg[i] = wd + (size_t)row * I_DIM + gc * 8;
        lb[i] = (wv * 32 + i * 8) * 64;
    }

    f32x4 acc[4][4];
    f32x4 z = {0.f, 0.f, 0.f, 0.f};
#pragma unroll
    for (int i = 0; i < 4; i++)
#pragma unroll
        for (int j = 0; j < 4; j++) acc[i][j] = z;

    int wm = (wv >> 1) * 64, wn = (wv & 1) * 64;
    int l16 = lane & 15, quad = lane >> 4;

    for (int kb = 0; kb < I_DIM; kb += 64) {
#pragma unroll
        for (int i = 0; i < 4; i++) {
            async16(ag[i] + kb, &As[lb[i]]);
            async16(bg[i] + kb, &Bs[lb[i]]);
        }
        __syncthreads();
#pragma unroll
        for (int ks = 0; ks < 2; ks++) {
            bf16x8 af[4], bf4[4];
#pragma unroll
            for (int i = 0; i < 4; i++) {
                int row = wm + i * 16 + l16;
                int pos = ((ks * 4 + quad) ^ (row & 7)) * 8;
                af[i] = *(const bf16x8*)(&As[row * 64 + pos]);
            }
#pragma unroll
            for (int j = 0; j < 4; j++) {
                int row = wn + j * 16 + l16;
                int pos = ((ks * 4 + quad) ^ (row & 7)) * 8;
                bf4[j] = *(const bf16x8*)(&Bs[row * 64 + pos]);
            }
#pragma unroll
            for (int i = 0; i < 4; i++)
#pragma unroll
                for (int j = 0; j < 4; j++)
                    acc[i][j] = __builtin_amdgcn_mfma_f32_16x16x32_bf16(af[i], bf4[j], acc[i][j], 0, 0, 0);
        }
        __syncthreads();
    }
#pragma unroll
    for (int i = 0; i < 4; i++) {
#pragma unroll
        for (int r = 0; r < 4; r++) {
            int row = wm + i * 16 + quad * 4 + r;
            float* orow = dbuf + (size_t)(base + row) * H_DIM + (size_t)nt * 128 + wn;
#pragma unroll
            for (int j = 0; j < 4; j++)
                orow[j * 16 + l16] = acc[i][j][r];
        }
    }
}

// ---------- combine: out[t] = dbuf[slot0] + dbuf[slot1] ----------
__global__ __launch_bounds__(256)
void combine_kernel(const float* __restrict__ dbuf, const int* __restrict__ slot_of,
                    float* __restrict__ out) {
    int t = blockIdx.x;
    int s0 = slot_of[2 * t], s1 = slot_of[2 * t + 1];
    const f32x4* r0 = (const f32x4*)(dbuf + (size_t)s0 * H_DIM);
    const f32x4* r1 = (const f32x4*)(dbuf + (size_t)s1 * H_DIM);
    f32x4* o = (f32x4*)(out + (size_t)t * H_DIM);
    int i = threadIdx.x;   // 256 threads x float4 = 1024 = H_DIM
    o[i] = r0[i] + r1[i];
}

extern "C" void kernel_launch(void* const* d_in, const int* in_sizes, int n_in,
                              void* d_out, int out_size, void* d_ws, size_t ws_size,
                              hipStream_t stream) {
    const float* x  = (const float*)d_in[0];
    const float* Wr = (const float*)d_in[1];
    const float* Wg = (const float*)d_in[2];
    const float* Wu = (const float*)d_in[3];
    const float* Wd = (const float*)d_in[4];
    float* out = (float*)d_out;
    char* ws = (char*)d_ws;

    size_t off = 0;
    unsigned short* xb   = (unsigned short*)(ws + off); off += (size_t)T_TOK * H_DIM * 2;
    unsigned short* wgT  = (unsigned short*)(ws + off); off += (size_t)E_NUM * H_DIM * I_DIM * 2;
    unsigned short* wuT  = (unsigned short*)(ws + off); off += (size_t)E_NUM * H_DIM * I_DIM * 2;
    unsigned short* wdT  = (unsigned short*)(ws + off); off += (size_t)E_NUM * H_DIM * I_DIM * 2;
    unsigned short* hbuf = (unsigned short*)(ws + off); off += (size_t)CAP * I_DIM * 2;
    float* dbuf    = (float*)(ws + off); off += (size_t)CAP * H_DIM * 4;
    int*   topidx  = (int*)(ws + off);   off += (size_t)T_TOK * 2 * 4;
    float* topw    = (float*)(ws + off); off += (size_t)T_TOK * 2 * 4;
    int*   slot_of = (int*)(ws + off);   off += (size_t)T_TOK * 2 * 4;
    int*   meta    = (int*)(ws + off);   off += 1024;
    int*   counts  = meta;          // 8
    int*   cursors = meta + 8;      // 8
    int*   padded  = meta + 16;     // 8
    int*   offs    = meta + 24;     // 9
    int*   ntiles  = meta + 33;     // 1
    int*   tile_e  = meta + 64;     // 72
    int*   tile_b  = meta + 136;    // 72
    int*   list_tok = (int*)(ws + off);  off += (size_t)CAP * 4;
    float* list_w   = (float*)(ws + off); off += (size_t)CAP * 4;

    hipMemsetAsync(counts, 0, 64, stream);  // counts + cursors

    router_kernel<<<T_TOK / 4, 256, 0, stream>>>(x, Wr, xb, topidx, topw, counts);
    transpose_all<<<dim3(32, 16, 24), 256, 0, stream>>>(Wg, Wu, Wd, wgT, wuT, wdT);
    offsets_pad_kernel<<<1, 256, 0, stream>>>(counts, padded, offs, tile_e, tile_b, ntiles, list_tok, list_w);
    scatter_kernel<<<(T_TOK * 2) / 256, 256, 0, stream>>>(topidx, topw, offs, cursors, list_tok, list_w, slot_of);
    gemm_gateup<<<dim3(MAXTILES, I_DIM / 128), 256, 0, stream>>>(xb, wgT, wuT, list_tok, list_w, tile_e, tile_b, ntiles, hbuf);
    gemm_down<<<dim3(MAXTILES, H_DIM / 128), 256, 0, stream>>>(hbuf, wdT, tile_e, tile_b, ntiles, dbuf);
    combine_kernel<<<T_TOK, 256, 0, stream>>>(dbuf, slot_of, out);
}

// Round 6
// 513.216 us; speedup vs baseline: 1.5410x; 1.1292x over previous
//
#include <hip/hip_runtime.h>
#include <stdint.h>

#define T_TOK 4096
#define H_DIM 1024
#define E_NUM 8
#define I_DIM 2048
#define CAP   9216   // max padded assignments
#define MAXTILES 72  // CAP/128

typedef float f32x4 __attribute__((ext_vector_type(4)));
typedef __bf16 bf16x8 __attribute__((ext_vector_type(8)));
typedef unsigned short u16x8 __attribute__((ext_vector_type(8)));
typedef unsigned short u16x4 __attribute__((ext_vector_type(4)));

__device__ __forceinline__ unsigned short f2bf(float f) {
    union { float f; unsigned int u; } v; v.f = f;
    unsigned int u = v.u;
    return (unsigned short)((u + 0x7fffu + ((u >> 16) & 1u)) >> 16);  // RNE
}
__device__ __forceinline__ float bf2f(unsigned short s) {
    union { unsigned int u; float f; } v; v.u = ((unsigned int)s) << 16; return v.f;
}

// async global->LDS, 16B per lane. LDS dest = wave-uniform base + lane*16.
__device__ __forceinline__ void async16(const unsigned short* g, unsigned short* l) {
    __builtin_amdgcn_global_load_lds(
        (const __attribute__((address_space(1))) unsigned int*)g,
        (__attribute__((address_space(3))) unsigned int*)l,
        16, 0, 0);
}

// ---------- router: wave per token, butterfly reduce; also x -> bf16 ----------
__global__ __launch_bounds__(256)
void router_kernel(const float* __restrict__ x, const float* __restrict__ Wr,
                   unsigned short* __restrict__ xb, int* __restrict__ topidx,
                   float* __restrict__ topw, int* __restrict__ counts) {
    int wv = threadIdx.x >> 6, lane = threadIdx.x & 63;
    int t = blockIdx.x * 4 + wv;
    const float* xrow = x + (size_t)t * H_DIM + lane * 16;
    const float* wrow = Wr + (size_t)lane * 16 * E_NUM;
    float acc[E_NUM];
#pragma unroll
    for (int e = 0; e < E_NUM; e++) acc[e] = 0.f;
    unsigned short xo[16];
#pragma unroll
    for (int c = 0; c < 4; c++) {
        f32x4 xv = *(const f32x4*)(xrow + c * 4);
#pragma unroll
        for (int k = 0; k < 4; k++) {
            float v = xv[k];
            xo[c * 4 + k] = f2bf(v);
            const float* wr = wrow + (c * 4 + k) * E_NUM;
#pragma unroll
            for (int e = 0; e < E_NUM; e++) acc[e] += v * wr[e];
        }
    }
    unsigned short* xbp = xb + (size_t)t * H_DIM + lane * 16;
    *(u16x8*)xbp = *(u16x8*)xo;
    *(u16x8*)(xbp + 8) = *(u16x8*)(xo + 8);
#pragma unroll
    for (int m = 1; m < 64; m <<= 1) {
#pragma unroll
        for (int e = 0; e < E_NUM; e++) acc[e] += __shfl_xor(acc[e], m);
    }
    if (lane == 0) {
        float v0 = -1e30f; int i0 = 0;
#pragma unroll
        for (int e = 0; e < E_NUM; e++) { if (acc[e] > v0) { v0 = acc[e]; i0 = e; } }
        float v1 = -1e30f; int i1 = 0;
#pragma unroll
        for (int e = 0; e < E_NUM; e++) { if (e != i0 && acc[e] > v1) { v1 = acc[e]; i1 = e; } }
        float e1 = __expf(v1 - v0);
        float s = 1.f + e1;
        topidx[t * 2 + 0] = i0; topidx[t * 2 + 1] = i1;
        topw[t * 2 + 0] = 1.f / s; topw[t * 2 + 1] = e1 / s;
        atomicAdd(&counts[i0], 1); atomicAdd(&counts[i1], 1);
    }
}

// ---------- offsets + XCD-interleaved tile map + pad fill ----------
__global__ __launch_bounds__(256)
void offsets_pad_kernel(const int* __restrict__ counts, int* __restrict__ padded,
                        int* __restrict__ offs, int* __restrict__ tile_e,
                        int* __restrict__ tile_base, int* __restrict__ ntiles,
                        int* __restrict__ list_tok, float* __restrict__ list_w) {
    __shared__ int sc[E_NUM], sp[E_NUM], so[E_NUM + 1], snt;
    __shared__ int ste[MAXTILES], stb[MAXTILES];
    int tid = threadIdx.x;
    if (tid < MAXTILES) { ste[tid] = 0; stb[tid] = 0; }
    if (tid == 0) {
        int off = 0, nt_e[E_NUM];
        for (int e = 0; e < E_NUM; e++) {
            sc[e] = counts[e];
            so[e] = off;
            int p = (sc[e] + 127) & ~127;
            sp[e] = p; nt_e[e] = p >> 7; off += p;
        }
        so[E_NUM] = off;
        int t2 = 0;
        // round-robin across experts: same-expert tiles ~8 apart -> same XCD
        for (int r = 0; r < MAXTILES; r++)
            for (int e = 0; e < E_NUM; e++)
                if (r < nt_e[e]) { ste[t2] = e; stb[t2] = so[e] + (r << 7); t2++; }
        snt = t2;
    }
    __syncthreads();
    if (tid < E_NUM) { padded[tid] = sp[tid]; offs[tid] = so[tid]; }
    if (tid == E_NUM) { offs[E_NUM] = so[E_NUM]; ntiles[0] = snt; }
    if (tid < MAXTILES) { tile_e[tid] = ste[tid]; tile_base[tid] = stb[tid]; }
#pragma unroll
    for (int e = 0; e < E_NUM; e++)
        for (int pos = sc[e] + tid; pos < sp[e]; pos += 256) {
            list_tok[so[e] + pos] = 0;
            list_w[so[e] + pos] = 0.f;
        }
}

// ---------- scatter assignments into per-expert lists + token->slot map ----------
__global__ __launch_bounds__(256)
void scatter_kernel(const int* __restrict__ topidx, const float* __restrict__ topw,
                    const int* __restrict__ offs, int* __restrict__ cursors,
                    int* __restrict__ list_tok, float* __restrict__ list_w,
                    int* __restrict__ slot_of) {
    int a = blockIdx.x * 256 + threadIdx.x;
    if (a >= T_TOK * 2) return;
    int e = topidx[a];
    int pos = atomicAdd(&cursors[e], 1);
    int slot = offs[e] + pos;
    list_tok[slot] = a >> 1;
    list_w[slot]   = topw[a];
    slot_of[a]     = slot;
}

// ---------- fused transpose + fp32->bf16 for all three weight tensors ----------
__global__ __launch_bounds__(256)
void transpose_all(const float* __restrict__ Wg, const float* __restrict__ Wu,
                   const float* __restrict__ Wd, unsigned short* __restrict__ wgT,
                   unsigned short* __restrict__ wuT, unsigned short* __restrict__ wdT) {
    __shared__ float tile[64][69];
    int z = blockIdx.z, bx = blockIdx.x, by = blockIdx.y;
    const float* in; unsigned short* out;
    int R, C, c0, r0;
    size_t mat = (size_t)H_DIM * I_DIM;
    if (z < 16) {               // Wg/Wu: R=H=1024, C=I=2048
        int e = z & 7;
        in  = (z < 8 ? Wg : Wu) + (size_t)e * mat;
        out = (z < 8 ? wgT : wuT) + (size_t)e * mat;
        R = H_DIM; C = I_DIM;
        c0 = bx * 64; r0 = by * 64;
    } else {                    // Wd: R=I=2048, C=H=1024
        int e = z - 16;
        in  = Wd + (size_t)e * mat;
        out = wdT + (size_t)e * mat;
        R = I_DIM; C = H_DIM;
        c0 = by * 64; r0 = bx * 64;
    }
    int tid = threadIdx.x;
    int lc = (tid & 15) * 4, lr = tid >> 4;
#pragma unroll
    for (int j = 0; j < 64; j += 16) {
        f32x4 v = *(const f32x4*)(in + (size_t)(r0 + lr + j) * C + c0 + lc);
        tile[lr + j][lc + 0] = v[0]; tile[lr + j][lc + 1] = v[1];
        tile[lr + j][lc + 2] = v[2]; tile[lr + j][lc + 3] = v[3];
    }
    __syncthreads();
    int r8 = (tid & 7) * 8;
#pragma unroll
    for (int cc = 0; cc < 64; cc += 32) {
        int c = cc + (tid >> 3);
        u16x8 u;
#pragma unroll
        for (int j = 0; j < 8; j++) u[j] = f2bf(tile[r8 + j][c]);
        *(u16x8*)(out + (size_t)(c0 + c) * R + r0 + r8) = u;
    }
}

// ---------- fused gate/up GEMM + SwiGLU ----------
// BM=128 BN=64 BK=64; 4 waves, wave-tile 64m x 32n per GEMM; acc = 64 VGPRs.
// (256,3): 3 blocks/CU (12 waves) vs r5's 2 — latency-hiding was the binder.
// LDS tiles unpadded (128B row stride) for global_load_lds; XOR chunk swizzle.
__global__ __launch_bounds__(256, 3)
void gemm_gateup(const unsigned short* __restrict__ xb, const unsigned short* __restrict__ wgT,
                 const unsigned short* __restrict__ wuT, const int* __restrict__ list_tok,
                 const float* __restrict__ list_w,
                 const int* __restrict__ tile_e, const int* __restrict__ tile_base,
                 const int* __restrict__ ntiles, unsigned short* __restrict__ hbuf) {
    int tile = blockIdx.x;
    if (tile >= ntiles[0]) return;
    int e = tile_e[tile], base = tile_base[tile], nt = blockIdx.y;

    __shared__ unsigned short As[128 * 64];
    __shared__ unsigned short Bgs[64 * 64];
    __shared__ unsigned short Bus[64 * 64];
    __shared__ int toks[128];
    __shared__ float wsh[128];

    int tid = threadIdx.x;
    if (tid < 128) { toks[tid] = list_tok[base + tid]; wsh[tid] = list_w[base + tid]; }
    __syncthreads();

    const unsigned short* wg = wgT + ((size_t)e * I_DIM + (size_t)nt * 64) * H_DIM;
    const unsigned short* wu = wuT + ((size_t)e * I_DIM + (size_t)nt * 64) * H_DIM;

    int wv = tid >> 6, lane = tid & 63;
    int sr = lane >> 3, sc = lane & 7, gc = sc ^ sr;

    // staging: per wave 4 A-instr (rows wv*32+i*8), 2 Bg + 2 Bu (rows wv*16+i*8)
    const unsigned short* ag[4]; const unsigned short* bgg[2]; const unsigned short* bug[2];
    int lbA[4], lbB[2];
#pragma unroll
    for (int i = 0; i < 4; i++) {
        int row = wv * 32 + i * 8 + sr;
        ag[i]  = xb + (size_t)toks[row] * H_DIM + gc * 8;
        lbA[i] = (wv * 32 + i * 8) * 64;
    }
#pragma unroll
    for (int i = 0; i < 2; i++) {
        int row = wv * 16 + i * 8 + sr;
        bgg[i] = wg + (size_t)row * H_DIM + gc * 8;
        bug[i] = wu + (size_t)row * H_DIM + gc * 8;
        lbB[i] = (wv * 16 + i * 8) * 64;
    }

    f32x4 accg[4][2], accu[4][2];
    f32x4 z = {0.f, 0.f, 0.f, 0.f};
#pragma unroll
    for (int i = 0; i < 4; i++)
#pragma unroll
        for (int j = 0; j < 2; j++) { accg[i][j] = z; accu[i][j] = z; }

    int wm = (wv >> 1) * 64, wn = (wv & 1) * 32;
    int l16 = lane & 15, quad = lane >> 4;

    for (int kb = 0; kb < H_DIM; kb += 64) {
#pragma unroll
        for (int i = 0; i < 4; i++) async16(ag[i] + kb, &As[lbA[i]]);
#pragma unroll
        for (int i = 0; i < 2; i++) {
            async16(bgg[i] + kb, &Bgs[lbB[i]]);
            async16(bug[i] + kb, &Bus[lbB[i]]);
        }
        __syncthreads();
#pragma unroll
        for (int ks = 0; ks < 2; ks++) {
            bf16x8 af[4], bg4[2], bu4[2];
#pragma unroll
            for (int i = 0; i < 4; i++) {
                int row = wm + i * 16 + l16;
                int pos = ((ks * 4 + quad) ^ (row & 7)) * 8;
                af[i] = *(const bf16x8*)(&As[row * 64 + pos]);
            }
#pragma unroll
            for (int j = 0; j < 2; j++) {
                int row = wn + j * 16 + l16;
                int pos = ((ks * 4 + quad) ^ (row & 7)) * 8;
                bg4[j] = *(const bf16x8*)(&Bgs[row * 64 + pos]);
                bu4[j] = *(const bf16x8*)(&Bus[row * 64 + pos]);
            }
#pragma unroll
            for (int i = 0; i < 4; i++)
#pragma unroll
                for (int j = 0; j < 2; j++) {
                    accg[i][j] = __builtin_amdgcn_mfma_f32_16x16x32_bf16(af[i], bg4[j], accg[i][j], 0, 0, 0);
                    accu[i][j] = __builtin_amdgcn_mfma_f32_16x16x32_bf16(af[i], bu4[j], accu[i][j], 0, 0, 0);
                }
        }
        __syncthreads();
    }
#pragma unroll
    for (int i = 0; i < 4; i++) {
#pragma unroll
        for (int r = 0; r < 4; r++) {
            int row = wm + i * 16 + quad * 4 + r;     // C/D: col=lane&15, row=quad*4+reg
            float wgt = wsh[row];
            size_t hb = (size_t)(base + row) * I_DIM + (size_t)nt * 64 + wn;
#pragma unroll
            for (int j = 0; j < 2; j++) {
                float g = accg[i][j][r];
                float u = accu[i][j][r];
                float sig = 1.f / (1.f + __expf(-g));
                hbuf[hb + j * 16 + l16] = f2bf(g * sig * u * wgt);
            }
        }
    }
}

// ---------- down GEMM: dbuf[slot] = h[slot] @ Wd, bf16 out ----------
// BM=128 BN=64 BK=64; acc = 32 VGPRs -> (256,4), 4 blocks/CU.
__global__ __launch_bounds__(256, 4)
void gemm_down(const unsigned short* __restrict__ hbuf, const unsigned short* __restrict__ wdT,
               const int* __restrict__ tile_e, const int* __restrict__ tile_base,
               const int* __restrict__ ntiles, unsigned short* __restrict__ dbuf) {
    int tile = blockIdx.x;
    if (tile >= ntiles[0]) return;
    int e = tile_e[tile], base = tile_base[tile], nt = blockIdx.y;

    __shared__ unsigned short As[128 * 64];
    __shared__ unsigned short Bs[64 * 64];

    int tid = threadIdx.x;
    const unsigned short* wd = wdT + ((size_t)e * H_DIM + (size_t)nt * 64) * I_DIM;

    int wv = tid >> 6, lane = tid & 63;
    int sr = lane >> 3, sc = lane & 7, gc = sc ^ sr;

    const unsigned short* ag[4]; const unsigned short* bg[2];
    int lbA[4], lbB[2];
#pragma unroll
    for (int i = 0; i < 4; i++) {
        int row = wv * 32 + i * 8 + sr;
        ag[i] = hbuf + (size_t)(base + row) * I_DIM + gc * 8;
        lbA[i] = (wv * 32 + i * 8) * 64;
    }
#pragma unroll
    for (int i = 0; i < 2; i++) {
        int row = wv * 16 + i * 8 + sr;
        bg[i] = wd + (size_t)row * I_DIM + gc * 8;
        lbB[i] = (wv * 16 + i * 8) * 64;
    }

    f32x4 acc[4][2];
    f32x4 z = {0.f, 0.f, 0.f, 0.f};
#pragma unroll
    for (int i = 0; i < 4; i++)
#pragma unroll
        for (int j = 0; j < 2; j++) acc[i][j] = z;

    int wm = (wv >> 1) * 64, wn = (wv & 1) * 32;
    int l16 = lane & 15, quad = lane >> 4;

    for (int kb = 0; kb < I_DIM; kb += 64) {
#pragma unroll
        for (int i = 0; i < 4; i++) async16(ag[i] + kb, &As[lbA[i]]);
#pragma unroll
        for (int i = 0; i < 2; i++) async16(bg[i] + kb, &Bs[lbB[i]]);
        __syncthreads();
#pragma unroll
        for (int ks = 0; ks < 2; ks++) {
            bf16x8 af[4], bf4[2];
#pragma unroll
            for (int i = 0; i < 4; i++) {
                int row = wm + i * 16 + l16;
                int pos = ((ks * 4 + quad) ^ (row & 7)) * 8;
                af[i] = *(const bf16x8*)(&As[row * 64 + pos]);
            }
#pragma unroll
            for (int j = 0; j < 2; j++) {
                int row = wn + j * 16 + l16;
                int pos = ((ks * 4 + quad) ^ (row & 7)) * 8;
                bf4[j] = *(const bf16x8*)(&Bs[row * 64 + pos]);
            }
#pragma unroll
            for (int i = 0; i < 4; i++)
#pragma unroll
                for (int j = 0; j < 2; j++)
                    acc[i][j] = __builtin_amdgcn_mfma_f32_16x16x32_bf16(af[i], bf4[j], acc[i][j], 0, 0, 0);
        }
        __syncthreads();
    }
#pragma unroll
    for (int i = 0; i < 4; i++) {
#pragma unroll
        for (int r = 0; r < 4; r++) {
            int row = wm + i * 16 + quad * 4 + r;
            unsigned short* orow = dbuf + (size_t)(base + row) * H_DIM + (size_t)nt * 64 + wn;
#pragma unroll
            for (int j = 0; j < 2; j++)
                orow[j * 16 + l16] = f2bf(acc[i][j][r]);
        }
    }
}

// ---------- combine: out[t] = dbuf[slot0] + dbuf[slot1] (bf16 in, fp32 out) ----------
__global__ __launch_bounds__(256)
void combine_kernel(const unsigned short* __restrict__ dbuf, const int* __restrict__ slot_of,
                    float* __restrict__ out) {
    int t = blockIdx.x;
    int s0 = slot_of[2 * t], s1 = slot_of[2 * t + 1];
    int i = threadIdx.x;   // 256 threads x 4 elems = 1024 = H_DIM
    u16x4 a = *(const u16x4*)(dbuf + (size_t)s0 * H_DIM + i * 4);
    u16x4 b = *(const u16x4*)(dbuf + (size_t)s1 * H_DIM + i * 4);
    f32x4 o;
#pragma unroll
    for (int k = 0; k < 4; k++) o[k] = bf2f(a[k]) + bf2f(b[k]);
    *(f32x4*)(out + (size_t)t * H_DIM + i * 4) = o;
}

extern "C" void kernel_launch(void* const* d_in, const int* in_sizes, int n_in,
                              void* d_out, int out_size, void* d_ws, size_t ws_size,
                              hipStream_t stream) {
    const float* x  = (const float*)d_in[0];
    const float* Wr = (const float*)d_in[1];
    const float* Wg = (const float*)d_in[2];
    const float* Wu = (const float*)d_in[3];
    const float* Wd = (const float*)d_in[4];
    float* out = (float*)d_out;
    char* ws = (char*)d_ws;

    size_t off = 0;
    unsigned short* xb   = (unsigned short*)(ws + off); off += (size_t)T_TOK * H_DIM * 2;
    unsigned short* wgT  = (unsigned short*)(ws + off); off += (size_t)E_NUM * H_DIM * I_DIM * 2;
    unsigned short* wuT  = (unsigned short*)(ws + off); off += (size_t)E_NUM * H_DIM * I_DIM * 2;
    unsigned short* wdT  = (unsigned short*)(ws + off); off += (size_t)E_NUM * H_DIM * I_DIM * 2;
    unsigned short* hbuf = (unsigned short*)(ws + off); off += (size_t)CAP * I_DIM * 2;
    unsigned short* dbuf = (unsigned short*)(ws + off); off += (size_t)CAP * H_DIM * 2;
    int*   topidx  = (int*)(ws + off);   off += (size_t)T_TOK * 2 * 4;
    float* topw    = (float*)(ws + off); off += (size_t)T_TOK * 2 * 4;
    int*   slot_of = (int*)(ws + off);   off += (size_t)T_TOK * 2 * 4;
    int*   meta    = (int*)(ws + off);   off += 1024;
    int*   counts  = meta;          // 8
    int*   cursors = meta + 8;      // 8
    int*   padded  = meta + 16;     // 8
    int*   offs    = meta + 24;     // 9
    int*   ntiles  = meta + 33;     // 1
    int*   tile_e  = meta + 64;     // 72
    int*   tile_b  = meta + 136;    // 72
    int*   list_tok = (int*)(ws + off);  off += (size_t)CAP * 4;
    float* list_w   = (float*)(ws + off); off += (size_t)CAP * 4;

    hipMemsetAsync(counts, 0, 64, stream);  // counts + cursors

    router_kernel<<<T_TOK / 4, 256, 0, stream>>>(x, Wr, xb, topidx, topw, counts);
    transpose_all<<<dim3(32, 16, 24), 256, 0, stream>>>(Wg, Wu, Wd, wgT, wuT, wdT);
    offsets_pad_kernel<<<1, 256, 0, stream>>>(counts, padded, offs, tile_e, tile_b, ntiles, list_tok, list_w);
    scatter_kernel<<<(T_TOK * 2) / 256, 256, 0, stream>>>(topidx, topw, offs, cursors, list_tok, list_w, slot_of);
    gemm_gateup<<<dim3(MAXTILES, I_DIM / 64), 256, 0, stream>>>(xb, wgT, wuT, list_tok, list_w, tile_e, tile_b, ntiles, hbuf);
    gemm_down<<<dim3(MAXTILES, H_DIM / 64), 256, 0, stream>>>(hbuf, wdT, tile_e, tile_b, ntiles, dbuf);
    combine_kernel<<<T_TOK, 256, 0, stream>>>(dbuf, slot_of, out);
}

// Round 7
// 406.993 us; speedup vs baseline: 1.9432x; 1.2610x over previous
//
#include <hip/hip_runtime.h>
#include <stdint.h>

#define T_TOK 4096
#define H_DIM 1024
#define E_NUM 8
#define I_DIM 2048
#define CAP   9216   // max padded assignments
#define MAXTILES 72  // CAP/128

typedef float f32x4 __attribute__((ext_vector_type(4)));
typedef __bf16 bf16x8 __attribute__((ext_vector_type(8)));
typedef unsigned short u16x8 __attribute__((ext_vector_type(8)));
typedef unsigned short u16x4 __attribute__((ext_vector_type(4)));

__device__ __forceinline__ unsigned short f2bf(float f) {
    union { float f; unsigned int u; } v; v.f = f;
    unsigned int u = v.u;
    return (unsigned short)((u + 0x7fffu + ((u >> 16) & 1u)) >> 16);  // RNE
}
__device__ __forceinline__ float bf2f(unsigned short s) {
    union { unsigned int u; float f; } v; v.u = ((unsigned int)s) << 16; return v.f;
}

// async global->LDS, 16B per lane. LDS dest = wave-uniform base + lane*16.
__device__ __forceinline__ void async16(const unsigned short* g, unsigned short* l) {
    __builtin_amdgcn_global_load_lds(
        (const __attribute__((address_space(1))) unsigned int*)g,
        (__attribute__((address_space(3))) unsigned int*)l,
        16, 0, 0);
}

// ---------- router: wave per token, butterfly reduce; x -> bf16. NO atomics ----------
// (r6: 8192 device atomicAdds to one cache line serialized at ~100cyc each = 106us)
__global__ __launch_bounds__(256)
void router_kernel(const float* __restrict__ x, const float* __restrict__ Wr,
                   unsigned short* __restrict__ xb, int* __restrict__ topidx,
                   float* __restrict__ topw) {
    int wv = threadIdx.x >> 6, lane = threadIdx.x & 63;
    int t = blockIdx.x * 4 + wv;
    const float* xrow = x + (size_t)t * H_DIM + lane * 16;
    const float* wrow = Wr + (size_t)lane * 16 * E_NUM;
    float acc[E_NUM];
#pragma unroll
    for (int e = 0; e < E_NUM; e++) acc[e] = 0.f;
    unsigned short xo[16];
#pragma unroll
    for (int c = 0; c < 4; c++) {
        f32x4 xv = *(const f32x4*)(xrow + c * 4);
#pragma unroll
        for (int k = 0; k < 4; k++) {
            float v = xv[k];
            xo[c * 4 + k] = f2bf(v);
            const float* wr = wrow + (c * 4 + k) * E_NUM;
#pragma unroll
            for (int e = 0; e < E_NUM; e++) acc[e] += v * wr[e];
        }
    }
    unsigned short* xbp = xb + (size_t)t * H_DIM + lane * 16;
    *(u16x8*)xbp = *(u16x8*)xo;
    *(u16x8*)(xbp + 8) = *(u16x8*)(xo + 8);
#pragma unroll
    for (int m = 1; m < 64; m <<= 1) {
#pragma unroll
        for (int e = 0; e < E_NUM; e++) acc[e] += __shfl_xor(acc[e], m);
    }
    if (lane == 0) {
        float v0 = -1e30f; int i0 = 0;
#pragma unroll
        for (int e = 0; e < E_NUM; e++) { if (acc[e] > v0) { v0 = acc[e]; i0 = e; } }
        float v1 = -1e30f; int i1 = 0;
#pragma unroll
        for (int e = 0; e < E_NUM; e++) { if (e != i0 && acc[e] > v1) { v1 = acc[e]; i1 = e; } }
        float e1 = __expf(v1 - v0);
        float s = 1.f + e1;
        topidx[t * 2 + 0] = i0; topidx[t * 2 + 1] = i1;
        topw[t * 2 + 0] = 1.f / s; topw[t * 2 + 1] = e1 / s;
    }
}

// ---------- single block: histogram (register+shfl, no global atomics) + offsets
//            + XCD-interleaved tile map + pad fill ----------
__global__ __launch_bounds__(256)
void offsets_pad_kernel(const int* __restrict__ topidx, int* __restrict__ padded,
                        int* __restrict__ offs, int* __restrict__ tile_e,
                        int* __restrict__ tile_base, int* __restrict__ ntiles,
                        int* __restrict__ list_tok, float* __restrict__ list_w) {
    __shared__ int sc[E_NUM], sp[E_NUM], so[E_NUM + 1], snt;
    __shared__ int ste[MAXTILES], stb[MAXTILES];
    __shared__ int whist[4][E_NUM];
    int tid = threadIdx.x;
    int wv = tid >> 6, lane = tid & 63;
    // histogram of 8192 assignments
    int cnt[E_NUM];
#pragma unroll
    for (int e = 0; e < E_NUM; e++) cnt[e] = 0;
    for (int a = tid; a < T_TOK * 2; a += 256) {
        int e = topidx[a];
#pragma unroll
        for (int k = 0; k < E_NUM; k++) cnt[k] += (e == k) ? 1 : 0;
    }
#pragma unroll
    for (int m = 1; m < 64; m <<= 1)
#pragma unroll
        for (int e = 0; e < E_NUM; e++) cnt[e] += __shfl_xor(cnt[e], m);
    if (lane == 0) {
#pragma unroll
        for (int e = 0; e < E_NUM; e++) whist[wv][e] = cnt[e];
    }
    if (tid < MAXTILES) { ste[tid] = 0; stb[tid] = 0; }
    __syncthreads();
    if (tid == 0) {
        int off = 0, nt_e[E_NUM];
        for (int e = 0; e < E_NUM; e++) {
            sc[e] = whist[0][e] + whist[1][e] + whist[2][e] + whist[3][e];
            so[e] = off;
            int p = (sc[e] + 127) & ~127;
            sp[e] = p; nt_e[e] = p >> 7; off += p;
        }
        so[E_NUM] = off;
        int t2 = 0;
        // round-robin across experts: same-expert tiles ~8 apart -> same XCD
        for (int r = 0; r < MAXTILES; r++)
            for (int e = 0; e < E_NUM; e++)
                if (r < nt_e[e]) { ste[t2] = e; stb[t2] = so[e] + (r << 7); t2++; }
        snt = t2;
    }
    __syncthreads();
    if (tid < E_NUM) { padded[tid] = sp[tid]; offs[tid] = so[tid]; }
    if (tid == E_NUM) { offs[E_NUM] = so[E_NUM]; ntiles[0] = snt; }
    if (tid < MAXTILES) { tile_e[tid] = ste[tid]; tile_base[tid] = stb[tid]; }
#pragma unroll
    for (int e = 0; e < E_NUM; e++)
        for (int pos = sc[e] + tid; pos < sp[e]; pos += 256) {
            list_tok[so[e] + pos] = 0;
            list_w[so[e] + pos] = 0.f;
        }
}

// ---------- scatter: block-aggregated cursors (256 global atomics total, not 8192) ----------
__global__ __launch_bounds__(256)
void scatter_kernel(const int* __restrict__ topidx, const float* __restrict__ topw,
                    const int* __restrict__ offs, int* __restrict__ cursors,
                    int* __restrict__ list_tok, float* __restrict__ list_w,
                    int* __restrict__ slot_of) {
    __shared__ int lcnt[E_NUM], gbase[E_NUM];
    int tid = threadIdx.x;
    if (tid < E_NUM) lcnt[tid] = 0;
    __syncthreads();
    int a = blockIdx.x * 256 + tid;
    int e = topidx[a];
    int lpos = atomicAdd(&lcnt[e], 1);      // LDS atomic: cheap
    __syncthreads();
    if (tid < E_NUM) gbase[tid] = atomicAdd(&cursors[tid], lcnt[tid]);
    __syncthreads();
    int slot = offs[e] + gbase[e] + lpos;
    list_tok[slot] = a >> 1;
    list_w[slot]   = topw[a];
    slot_of[a]     = slot;
}

// ---------- fused transpose + fp32->bf16 for all three weight tensors ----------
__global__ __launch_bounds__(256)
void transpose_all(const float* __restrict__ Wg, const float* __restrict__ Wu,
                   const float* __restrict__ Wd, unsigned short* __restrict__ wgT,
                   unsigned short* __restrict__ wuT, unsigned short* __restrict__ wdT) {
    __shared__ float tile[64][69];
    int z = blockIdx.z, bx = blockIdx.x, by = blockIdx.y;
    const float* in; unsigned short* out;
    int R, C, c0, r0;
    size_t mat = (size_t)H_DIM * I_DIM;
    if (z < 16) {               // Wg/Wu: R=H=1024, C=I=2048
        int e = z & 7;
        in  = (z < 8 ? Wg : Wu) + (size_t)e * mat;
        out = (z < 8 ? wgT : wuT) + (size_t)e * mat;
        R = H_DIM; C = I_DIM;
        c0 = bx * 64; r0 = by * 64;
    } else {                    // Wd: R=I=2048, C=H=1024
        int e = z - 16;
        in  = Wd + (size_t)e * mat;
        out = wdT + (size_t)e * mat;
        R = I_DIM; C = H_DIM;
        c0 = by * 64; r0 = bx * 64;
    }
    int tid = threadIdx.x;
    int lc = (tid & 15) * 4, lr = tid >> 4;
#pragma unroll
    for (int j = 0; j < 64; j += 16) {
        f32x4 v = *(const f32x4*)(in + (size_t)(r0 + lr + j) * C + c0 + lc);
        tile[lr + j][lc + 0] = v[0]; tile[lr + j][lc + 1] = v[1];
        tile[lr + j][lc + 2] = v[2]; tile[lr + j][lc + 3] = v[3];
    }
    __syncthreads();
    int r8 = (tid & 7) * 8;
#pragma unroll
    for (int cc = 0; cc < 64; cc += 32) {
        int c = cc + (tid >> 3);
        u16x8 u;
#pragma unroll
        for (int j = 0; j < 8; j++) u[j] = f2bf(tile[r8 + j][c]);
        *(u16x8*)(out + (size_t)(c0 + c) * R + r0 + r8) = u;
    }
}

// ---------- fused gate/up GEMM + SwiGLU ----------
// BM=128 BN=64 BK=64; 4 waves, wave-tile 64m x 32n per GEMM; acc = 64 VGPRs.
// (256,3): 3 blocks/CU. LDS unpadded (128B stride) for global_load_lds; XOR swizzle.
__global__ __launch_bounds__(256, 3)
void gemm_gateup(const unsigned short* __restrict__ xb, const unsigned short* __restrict__ wgT,
                 const unsigned short* __restrict__ wuT, const int* __restrict__ list_tok,
                 const float* __restrict__ list_w,
                 const int* __restrict__ tile_e, const int* __restrict__ tile_base,
                 const int* __restrict__ ntiles, unsigned short* __restrict__ hbuf) {
    int tile = blockIdx.x;
    if (tile >= ntiles[0]) return;
    int e = tile_e[tile], base = tile_base[tile], nt = blockIdx.y;

    __shared__ unsigned short As[128 * 64];
    __shared__ unsigned short Bgs[64 * 64];
    __shared__ unsigned short Bus[64 * 64];
    __shared__ int toks[128];
    __shared__ float wsh[128];

    int tid = threadIdx.x;
    if (tid < 128) { toks[tid] = list_tok[base + tid]; wsh[tid] = list_w[base + tid]; }
    __syncthreads();

    const unsigned short* wg = wgT + ((size_t)e * I_DIM + (size_t)nt * 64) * H_DIM;
    const unsigned short* wu = wuT + ((size_t)e * I_DIM + (size_t)nt * 64) * H_DIM;

    int wv = tid >> 6, lane = tid & 63;
    int sr = lane >> 3, sc = lane & 7, gc = sc ^ sr;

    const unsigned short* ag[4]; const unsigned short* bgg[2]; const unsigned short* bug[2];
    int lbA[4], lbB[2];
#pragma unroll
    for (int i = 0; i < 4; i++) {
        int row = wv * 32 + i * 8 + sr;
        ag[i]  = xb + (size_t)toks[row] * H_DIM + gc * 8;
        lbA[i] = (wv * 32 + i * 8) * 64;
    }
#pragma unroll
    for (int i = 0; i < 2; i++) {
        int row = wv * 16 + i * 8 + sr;
        bgg[i] = wg + (size_t)row * H_DIM + gc * 8;
        bug[i] = wu + (size_t)row * H_DIM + gc * 8;
        lbB[i] = (wv * 16 + i * 8) * 64;
    }

    f32x4 accg[4][2], accu[4][2];
    f32x4 z = {0.f, 0.f, 0.f, 0.f};
#pragma unroll
    for (int i = 0; i < 4; i++)
#pragma unroll
        for (int j = 0; j < 2; j++) { accg[i][j] = z; accu[i][j] = z; }

    int wm = (wv >> 1) * 64, wn = (wv & 1) * 32;
    int l16 = lane & 15, quad = lane >> 4;

    for (int kb = 0; kb < H_DIM; kb += 64) {
#pragma unroll
        for (int i = 0; i < 4; i++) async16(ag[i] + kb, &As[lbA[i]]);
#pragma unroll
        for (int i = 0; i < 2; i++) {
            async16(bgg[i] + kb, &Bgs[lbB[i]]);
            async16(bug[i] + kb, &Bus[lbB[i]]);
        }
        __syncthreads();
#pragma unroll
        for (int ks = 0; ks < 2; ks++) {
            bf16x8 af[4], bg4[2], bu4[2];
#pragma unroll
            for (int i = 0; i < 4; i++) {
                int row = wm + i * 16 + l16;
                int pos = ((ks * 4 + quad) ^ (row & 7)) * 8;
                af[i] = *(const bf16x8*)(&As[row * 64 + pos]);
            }
#pragma unroll
            for (int j = 0; j < 2; j++) {
                int row = wn + j * 16 + l16;
                int pos = ((ks * 4 + quad) ^ (row & 7)) * 8;
                bg4[j] = *(const bf16x8*)(&Bgs[row * 64 + pos]);
                bu4[j] = *(const bf16x8*)(&Bus[row * 64 + pos]);
            }
#pragma unroll
            for (int i = 0; i < 4; i++)
#pragma unroll
                for (int j = 0; j < 2; j++) {
                    accg[i][j] = __builtin_amdgcn_mfma_f32_16x16x32_bf16(af[i], bg4[j], accg[i][j], 0, 0, 0);
                    accu[i][j] = __builtin_amdgcn_mfma_f32_16x16x32_bf16(af[i], bu4[j], accu[i][j], 0, 0, 0);
                }
        }
        __syncthreads();
    }
#pragma unroll
    for (int i = 0; i < 4; i++) {
#pragma unroll
        for (int r = 0; r < 4; r++) {
            int row = wm + i * 16 + quad * 4 + r;     // C/D: col=lane&15, row=quad*4+reg
            float wgt = wsh[row];
            size_t hb = (size_t)(base + row) * I_DIM + (size_t)nt * 64 + wn;
#pragma unroll
            for (int j = 0; j < 2; j++) {
                float g = accg[i][j][r];
                float u = accu[i][j][r];
                float sig = 1.f / (1.f + __expf(-g));
                hbuf[hb + j * 16 + l16] = f2bf(g * sig * u * wgt);
            }
        }
    }
}

// ---------- down GEMM: dbuf[slot] = h[slot] @ Wd, bf16 out ----------
// BM=128 BN=64 BK=64; acc = 32 VGPRs -> (256,4), 4 blocks/CU.
__global__ __launch_bounds__(256, 4)
void gemm_down(const unsigned short* __restrict__ hbuf, const unsigned short* __restrict__ wdT,
               const int* __restrict__ tile_e, const int* __restrict__ tile_base,
               const int* __restrict__ ntiles, unsigned short* __restrict__ dbuf) {
    int tile = blockIdx.x;
    if (tile >= ntiles[0]) return;
    int e = tile_e[tile], base = tile_base[tile], nt = blockIdx.y;

    __shared__ unsigned short As[128 * 64];
    __shared__ unsigned short Bs[64 * 64];

    int tid = threadIdx.x;
    const unsigned short* wd = wdT + ((size_t)e * H_DIM + (size_t)nt * 64) * I_DIM;

    int wv = tid >> 6, lane = tid & 63;
    int sr = lane >> 3, sc = lane & 7, gc = sc ^ sr;

    const unsigned short* ag[4]; const unsigned short* bg[2];
    int lbA[4], lbB[2];
#pragma unroll
    for (int i = 0; i < 4; i++) {
        int row = wv * 32 + i * 8 + sr;
        ag[i] = hbuf + (size_t)(base + row) * I_DIM + gc * 8;
        lbA[i] = (wv * 32 + i * 8) * 64;
    }
#pragma unroll
    for (int i = 0; i < 2; i++) {
        int row = wv * 16 + i * 8 + sr;
        bg[i] = wd + (size_t)row * I_DIM + gc * 8;
        lbB[i] = (wv * 16 + i * 8) * 64;
    }

    f32x4 acc[4][2];
    f32x4 z = {0.f, 0.f, 0.f, 0.f};
#pragma unroll
    for (int i = 0; i < 4; i++)
#pragma unroll
        for (int j = 0; j < 2; j++) acc[i][j] = z;

    int wm = (wv >> 1) * 64, wn = (wv & 1) * 32;
    int l16 = lane & 15, quad = lane >> 4;

    for (int kb = 0; kb < I_DIM; kb += 64) {
#pragma unroll
        for (int i = 0; i < 4; i++) async16(ag[i] + kb, &As[lbA[i]]);
#pragma unroll
        for (int i = 0; i < 2; i++) async16(bg[i] + kb, &Bs[lbB[i]]);
        __syncthreads();
#pragma unroll
        for (int ks = 0; ks < 2; ks++) {
            bf16x8 af[4], bf4[2];
#pragma unroll
            for (int i = 0; i < 4; i++) {
                int row = wm + i * 16 + l16;
                int pos = ((ks * 4 + quad) ^ (row & 7)) * 8;
                af[i] = *(const bf16x8*)(&As[row * 64 + pos]);
            }
#pragma unroll
            for (int j = 0; j < 2; j++) {
                int row = wn + j * 16 + l16;
                int pos = ((ks * 4 + quad) ^ (row & 7)) * 8;
                bf4[j] = *(const bf16x8*)(&Bs[row * 64 + pos]);
            }
#pragma unroll
            for (int i = 0; i < 4; i++)
#pragma unroll
                for (int j = 0; j < 2; j++)
                    acc[i][j] = __builtin_amdgcn_mfma_f32_16x16x32_bf16(af[i], bf4[j], acc[i][j], 0, 0, 0);
        }
        __syncthreads();
    }
#pragma unroll
    for (int i = 0; i < 4; i++) {
#pragma unroll
        for (int r = 0; r < 4; r++) {
            int row = wm + i * 16 + quad * 4 + r;
            unsigned short* orow = dbuf + (size_t)(base + row) * H_DIM + (size_t)nt * 64 + wn;
#pragma unroll
            for (int j = 0; j < 2; j++)
                orow[j * 16 + l16] = f2bf(acc[i][j][r]);
        }
    }
}

// ---------- combine: out[t] = dbuf[slot0] + dbuf[slot1] (bf16 in, fp32 out) ----------
__global__ __launch_bounds__(256)
void combine_kernel(const unsigned short* __restrict__ dbuf, const int* __restrict__ slot_of,
                    float* __restrict__ out) {
    int t = blockIdx.x;
    int s0 = slot_of[2 * t], s1 = slot_of[2 * t + 1];
    int i = threadIdx.x;   // 256 threads x 4 elems = 1024 = H_DIM
    u16x4 a = *(const u16x4*)(dbuf + (size_t)s0 * H_DIM + i * 4);
    u16x4 b = *(const u16x4*)(dbuf + (size_t)s1 * H_DIM + i * 4);
    f32x4 o;
#pragma unroll
    for (int k = 0; k < 4; k++) o[k] = bf2f(a[k]) + bf2f(b[k]);
    *(f32x4*)(out + (size_t)t * H_DIM + i * 4) = o;
}

extern "C" void kernel_launch(void* const* d_in, const int* in_sizes, int n_in,
                              void* d_out, int out_size, void* d_ws, size_t ws_size,
                              hipStream_t stream) {
    const float* x  = (const float*)d_in[0];
    const float* Wr = (const float*)d_in[1];
    const float* Wg = (const float*)d_in[2];
    const float* Wu = (const float*)d_in[3];
    const float* Wd = (const float*)d_in[4];
    float* out = (float*)d_out;
    char* ws = (char*)d_ws;

    size_t off = 0;
    unsigned short* xb   = (unsigned short*)(ws + off); off += (size_t)T_TOK * H_DIM * 2;
    unsigned short* wgT  = (unsigned short*)(ws + off); off += (size_t)E_NUM * H_DIM * I_DIM * 2;
    unsigned short* wuT  = (unsigned short*)(ws + off); off += (size_t)E_NUM * H_DIM * I_DIM * 2;
    unsigned short* wdT  = (unsigned short*)(ws + off); off += (size_t)E_NUM * H_DIM * I_DIM * 2;
    unsigned short* hbuf = (unsigned short*)(ws + off); off += (size_t)CAP * I_DIM * 2;
    unsigned short* dbuf = (unsigned short*)(ws + off); off += (size_t)CAP * H_DIM * 2;
    int*   topidx  = (int*)(ws + off);   off += (size_t)T_TOK * 2 * 4;
    float* topw    = (float*)(ws + off); off += (size_t)T_TOK * 2 * 4;
    int*   slot_of = (int*)(ws + off);   off += (size_t)T_TOK * 2 * 4;
    int*   meta    = (int*)(ws + off);   off += 1024;
    int*   cursors = meta + 8;      // 8
    int*   padded  = meta + 16;     // 8
    int*   offs    = meta + 24;     // 9
    int*   ntiles  = meta + 33;     // 1
    int*   tile_e  = meta + 64;     // 72
    int*   tile_b  = meta + 136;    // 72
    int*   list_tok = (int*)(ws + off);  off += (size_t)CAP * 4;
    float* list_w   = (float*)(ws + off); off += (size_t)CAP * 4;

    hipMemsetAsync(meta, 0, 64, stream);  // cursors

    router_kernel<<<T_TOK / 4, 256, 0, stream>>>(x, Wr, xb, topidx, topw);
    transpose_all<<<dim3(32, 16, 24), 256, 0, stream>>>(Wg, Wu, Wd, wgT, wuT, wdT);
    offsets_pad_kernel<<<1, 256, 0, stream>>>(topidx, padded, offs, tile_e, tile_b, ntiles, list_tok, list_w);
    scatter_kernel<<<(T_TOK * 2) / 256, 256, 0, stream>>>(topidx, topw, offs, cursors, list_tok, list_w, slot_of);
    gemm_gateup<<<dim3(MAXTILES, I_DIM / 64), 256, 0, stream>>>(xb, wgT, wuT, list_tok, list_w, tile_e, tile_b, ntiles, hbuf);
    gemm_down<<<dim3(MAXTILES, H_DIM / 64), 256, 0, stream>>>(hbuf, wdT, tile_e, tile_b, ntiles, dbuf);
    combine_kernel<<<T_TOK, 256, 0, stream>>>(dbuf, slot_of, out);
}